// Round 1
// baseline (1582.193 us; speedup 1.0000x reference)
//
#include <hip/hip_runtime.h>
#include <hip/hip_bf16.h>

// Problem: B=16, C=256, H=64, L=40, TD=768, NC=8, EMB=392
// Pipeline: map_visu=tanh(cbs(img,Wv)) ; lang MLP -> (yc,xc) ; sigma via Ws-conv mean;
// gaussian -> gamma/beta (8ch 1x1) -> g,bmax ; v=l2norm(g*mv+bmax) ; cbs Wf1 1x1 ;
// cbs Wf2 3x3 pad1 ; Wf3 1x1 + bf3 ; out = l2norm(img + v_film)  (aw=tanh(0)=0 general)

#define DEVFN static __device__ __forceinline__

DEVFN float sigmoidf_(float x) { return 1.f / (1.f + expf(-x)); }
DEVFN float siluf_(float y) { return y / (1.f + expf(-y)); }

// ---------------- prep: transpose weights for coalesced staging ----------------
// WvT/WT1/WT3: [ci][co] (256x256). WT2: [kk=ky*3+kx][ci][co] (9x256x256)
__global__ void prep_kernel(const float* __restrict__ Wv, const float* __restrict__ Wf1,
                            const float* __restrict__ Wf3, const float* __restrict__ Wf2,
                            float* __restrict__ WvT, float* __restrict__ WT1,
                            float* __restrict__ WT3, float* __restrict__ WT2) {
    int idx = blockIdx.x * 256 + threadIdx.x;
    if (idx < 65536) {
        int ci = idx >> 8, co = idx & 255;
        int src = co * 256 + ci;
        WvT[idx] = Wv[src];
        WT1[idx] = Wf1[src];
        WT3[idx] = Wf3[src];
    }
    int o = idx - 65536;
    if (o >= 0 && o < 589824) {
        int kk = o >> 16;           // 0..8
        int rem = o & 65535;
        int ci = rem >> 8, co = rem & 255;
        WT2[o] = Wf2[(co * 256 + ci) * 9 + kk];
    }
}

// ---------------- lang average ----------------
__global__ void lang_kernel(const float* __restrict__ flang, const int* __restrict__ mask,
                            float* __restrict__ fa) {
    __shared__ float inc[40];
    __shared__ float isum;
    int b = blockIdx.x, t = threadIdx.x;
    if (t == 0) {
        float cum[40];
        float c = 0.f;
        for (int l = 0; l < 40; ++l) { c += (float)mask[b * 40 + l]; cum[l] = c; }
        float tot = c, s = 0.f;
        for (int l = 0; l < 40; ++l) {
            float m = (float)mask[b * 40 + l];
            float v = (cum[l] > 1.f && cum[l] < tot) ? m : 0.f;
            inc[l] = v; s += v;
        }
        isum = s;
    }
    __syncthreads();
    for (int d = t; d < 768; d += 256) {
        float a = 0.f;
        for (int l = 0; l < 40; ++l) a += flang[(size_t)(b * 40 + l) * 768 + d] * inc[l];
        fa[b * 768 + d] = a / isum;
    }
}

// ---------------- lang MLP -> yc/xc ----------------
__global__ void mlp_kernel(const float* __restrict__ fa_g, const float* __restrict__ W1,
                           const float* __restrict__ b1, const float* __restrict__ W2,
                           const float* __restrict__ b2, float* __restrict__ ycxc) {
    __shared__ float fa[768];
    __shared__ float h[392];
    __shared__ float o[16];
    int b = blockIdx.x, t = threadIdx.x;
    for (int k = t; k < 768; k += 448) fa[k] = fa_g[b * 768 + k];
    __syncthreads();
    if (t < 392) {
        float a = b1[t];
        const float* w = W1 + (size_t)t * 768;
        for (int k = 0; k < 768; ++k) a = fmaf(fa[k], w[k], a);
        h[t] = a;
    }
    __syncthreads();
    if (t < 16) {
        float a = b2[t];
        const float* w = W2 + (size_t)t * 392;
        for (int k = 0; k < 392; ++k) a = fmaf(h[k], w[k], a);
        o[t] = sigmoidf_(a);
    }
    __syncthreads();
    if (t < 8) {
        ycxc[b * 8 + t]       = (float)(int)(o[2 * t] * 64.f);
        ycxc[128 + b * 8 + t] = (float)(int)(o[2 * t + 1] * 64.f);
    }
}

// ---------------- window sums for sigma (valid conv mean trick) ----------------
__global__ void wsum_kernel(const float* __restrict__ img, float* __restrict__ S) {
    __shared__ float red[9 * 256];
    int bc = blockIdx.x;            // b*256 + ci
    int t = threadIdx.x;
    float s[9];
#pragma unroll
    for (int k = 0; k < 9; ++k) s[k] = 0.f;
    const float* p = img + (size_t)bc * 4096;
    for (int j = 0; j < 16; ++j) {
        int idx = t + j * 256;
        int y = idx >> 6, x = idx & 63;
        float v = p[idx];
#pragma unroll
        for (int ky = 0; ky < 3; ++ky) {
            if (y < ky || y > ky + 61) continue;
#pragma unroll
            for (int kx = 0; kx < 3; ++kx) {
                if (x < kx || x > kx + 61) continue;
                s[ky * 3 + kx] += v;
            }
        }
    }
#pragma unroll
    for (int k = 0; k < 9; ++k) red[k * 256 + t] = s[k];
    __syncthreads();
    for (int st = 128; st > 0; st >>= 1) {
        if (t < st) {
#pragma unroll
            for (int k = 0; k < 9; ++k) red[k * 256 + t] += red[k * 256 + t + st];
        }
        __syncthreads();
    }
    if (t < 9) S[(size_t)bc * 9 + t] = red[t * 256];
}

__global__ void sigw_kernel(const float* __restrict__ Ws, const float* __restrict__ S,
                            const float* __restrict__ bs, float* __restrict__ sigw) {
    __shared__ float red[8 * 256];
    int b = blockIdx.x, t = threadIdx.x;    // t = ci
    float sv[9];
    const float* Sp = S + (size_t)(b * 256 + t) * 9;
#pragma unroll
    for (int k = 0; k < 9; ++k) sv[k] = Sp[k];
#pragma unroll
    for (int co = 0; co < 8; ++co) {
        const float* wp = Ws + (size_t)(co * 256 + t) * 9;
        float a = 0.f;
#pragma unroll
        for (int k = 0; k < 9; ++k) a = fmaf(wp[k], sv[k], a);
        red[co * 256 + t] = a;
    }
    __syncthreads();
    for (int st = 128; st > 0; st >>= 1) {
        if (t < st) {
#pragma unroll
            for (int co = 0; co < 8; ++co) red[co * 256 + t] += red[co * 256 + t + st];
        }
        __syncthreads();
    }
    if (t < 8) sigw[b * 8 + t] = sigmoidf_(red[t * 256] / 3844.f + bs[t]);
}

// ---------------- gaussian -> gamma/beta -> g, bmax ----------------
__global__ void gauss_kernel(const float* __restrict__ ycxc, const float* __restrict__ sigw,
                             const float* __restrict__ sigma_w,
                             const float* __restrict__ Wg, const float* __restrict__ sg,
                             const float* __restrict__ bg,
                             const float* __restrict__ Wb, const float* __restrict__ sb,
                             const float* __restrict__ bb,
                             float* __restrict__ g, float* __restrict__ bm) {
    int blk = blockIdx.x;
    int b = blk >> 6, y = blk & 63;
    int x = threadIdx.x;
    float sx = sigma_w[0] * 64.f;
    float w[8];
#pragma unroll
    for (int n = 0; n < 8; ++n) {
        float yc = ycxc[b * 8 + n], xc = ycxc[128 + b * 8 + n];
        float sy = sx * sigw[b * 8 + n];
        float dy = (float)y - yc, dx = (float)x - xc;
        w[n] = expf(-(dy * dy / (2.f * sy * sy) + dx * dx / (2.f * sx * sx)));
    }
    float gacc = 0.f, bmax = -3.4e38f;
#pragma unroll
    for (int n = 0; n < 8; ++n) {
        float a1 = 0.f, a2 = 0.f;
#pragma unroll
        for (int m = 0; m < 8; ++m) {
            a1 = fmaf(Wg[n * 8 + m], w[m], a1);
            a2 = fmaf(Wb[n * 8 + m], w[m], a2);
        }
        float ga = tanhf(siluf_(a1 * sg[n] + bg[n]));
        float be = tanhf(siluf_(a2 * sb[n] + bb[n]));
        gacc += ga;
        bmax = fmaxf(bmax, be);
    }
    g[(size_t)(b * 64 + y) * 64 + x] = gacc * 0.125f;
    bm[(size_t)(b * 64 + y) * 64 + x] = bmax;
}

// ---------------- 1x1 conv 256->256, register-blocked 8co x 8x ----------------
template <int TANH>
__global__ __launch_bounds__(256) void conv1x1_kernel(const float* __restrict__ in,
                                                      const float* __restrict__ wT,
                                                      const float* __restrict__ sc,
                                                      const float* __restrict__ bi,
                                                      float* __restrict__ out) {
    __shared__ float act[32 * 64];     // [ci][x]
    __shared__ float wl[32 * 256];     // [ci][co]
    int blk = blockIdx.x;
    int b = blk >> 6, y = blk & 63;
    int t = threadIdx.x;
    int xt = t & 7, ct = t >> 3;
    int x0 = xt * 8, co0 = ct * 8;
    const float* inb = in + (size_t)b * 1048576 + y * 64;
    float acc[8][8];
#pragma unroll
    for (int j = 0; j < 8; ++j)
#pragma unroll
        for (int k = 0; k < 8; ++k) acc[j][k] = 0.f;

    for (int c0 = 0; c0 < 256; c0 += 32) {
#pragma unroll
        for (int j = 0; j < 8; ++j) {
            int e = t + j * 256;
            int ci = e >> 6, x = e & 63;
            act[e] = inb[(size_t)(c0 + ci) * 4096 + x];
        }
        const float* wp = wT + (size_t)c0 * 256;
#pragma unroll
        for (int j = 0; j < 32; ++j) wl[t + j * 256] = wp[t + j * 256];
        __syncthreads();
#pragma unroll 4
        for (int i = 0; i < 32; ++i) {
            float av[8], wv[8];
            *(float4*)&av[0] = *(const float4*)&act[i * 64 + x0];
            *(float4*)&av[4] = *(const float4*)&act[i * 64 + x0 + 4];
            *(float4*)&wv[0] = *(const float4*)&wl[i * 256 + co0];
            *(float4*)&wv[4] = *(const float4*)&wl[i * 256 + co0 + 4];
#pragma unroll
            for (int j = 0; j < 8; ++j)
#pragma unroll
                for (int k = 0; k < 8; ++k) acc[j][k] = fmaf(wv[j], av[k], acc[j][k]);
        }
        __syncthreads();
    }
#pragma unroll
    for (int j = 0; j < 8; ++j) {
        int co = co0 + j;
        float s = sc[co], bb2 = bi[co];
        float r[8];
#pragma unroll
        for (int k = 0; k < 8; ++k) {
            float yv = fmaf(acc[j][k], s, bb2);
            float sl = yv / (1.f + expf(-yv));
            r[k] = TANH ? tanhf(sl) : sl;
        }
        float* op = out + (size_t)(b * 256 + co) * 4096 + y * 64 + x0;
        *(float4*)&op[0] = *(float4*)&r[0];
        *(float4*)&op[4] = *(float4*)&r[4];
    }
}

// ---------------- film: v = l2norm(g*mv + bmax) ----------------
__global__ __launch_bounds__(256) void film_kernel(const float* __restrict__ mv,
                                                   const float* __restrict__ g,
                                                   const float* __restrict__ bm,
                                                   float* __restrict__ out) {
    __shared__ float pr[4 * 64];
    __shared__ float invs[64];
    int blk = blockIdx.x;
    int b = blk >> 6, y = blk & 63;
    int t = threadIdx.x;
    int x = t & 63, cg = t >> 6;
    float gv = g[(size_t)(b * 64 + y) * 64 + x];
    float bv = bm[(size_t)(b * 64 + y) * 64 + x];
    const float* mp = mv + (size_t)b * 1048576 + y * 64 + x;
    float ss = 0.f;
    for (int co = cg; co < 256; co += 4) {
        float v = fmaf(gv, mp[(size_t)co * 4096], bv);
        ss += v * v;
    }
    pr[cg * 64 + x] = ss;
    __syncthreads();
    if (t < 64)
        invs[t] = 1.f / fmaxf(sqrtf(pr[t] + pr[64 + t] + pr[128 + t] + pr[192 + t]), 1e-12f);
    __syncthreads();
    float iv = invs[x];
    float* op = out + (size_t)b * 1048576 + y * 64 + x;
    for (int co = cg; co < 256; co += 4) {
        float v = fmaf(gv, mp[(size_t)co * 4096], bv);
        op[(size_t)co * 4096] = v * iv;
    }
}

// ---------------- 3x3 conv 256->256 pad1 + silu ----------------
__global__ __launch_bounds__(256) void conv3x3_kernel(const float* __restrict__ in,
                                                      const float* __restrict__ wT2,
                                                      const float* __restrict__ sc,
                                                      const float* __restrict__ bi,
                                                      float* __restrict__ out) {
    __shared__ float a3[4 * 3 * 66];       // [ci][row][x+1], rows y-1..y+1
    __shared__ float wl[9 * 4 * 256];      // [kk][ci][co]
    int blk = blockIdx.x;
    int b = blk >> 6, y = blk & 63;
    int t = threadIdx.x;
    int xt = t & 7, ct = t >> 3;
    int x0 = xt * 8, co0 = ct * 8;
    const float* inb = in + (size_t)b * 1048576;
    float acc[8][8];
#pragma unroll
    for (int j = 0; j < 8; ++j)
#pragma unroll
        for (int k = 0; k < 8; ++k) acc[j][k] = 0.f;

    for (int c0 = 0; c0 < 256; c0 += 4) {
        if (t < 24) {
            int ci = t / 6, rp = t % 6;
            int r = rp >> 1, side = rp & 1;
            a3[(ci * 3 + r) * 66 + (side ? 65 : 0)] = 0.f;
        }
#pragma unroll
        for (int j = 0; j < 3; ++j) {
            int e = t + j * 256;
            int x = e & 63, rc = e >> 6;
            int ci = rc / 3, r = rc - ci * 3;
            int yy = y + r - 1;
            float v = (yy >= 0 && yy < 64) ? inb[((size_t)(c0 + ci) * 64 + yy) * 64 + x] : 0.f;
            a3[(ci * 3 + r) * 66 + 1 + x] = v;
        }
#pragma unroll
        for (int j = 0; j < 36; ++j) {
            int e = t + j * 256;
            int kk = e >> 10, rem = e & 1023;
            wl[e] = wT2[(size_t)kk * 65536 + c0 * 256 + rem];
        }
        __syncthreads();
#pragma unroll
        for (int ci = 0; ci < 4; ++ci) {
#pragma unroll
            for (int ky = 0; ky < 3; ++ky) {
                float av[10];
#pragma unroll
                for (int u = 0; u < 10; ++u) av[u] = a3[(ci * 3 + ky) * 66 + x0 + u];
#pragma unroll
                for (int kx = 0; kx < 3; ++kx) {
                    const float* wrow = &wl[((ky * 3 + kx) * 4 + ci) * 256 + co0];
                    float wv[8];
                    *(float4*)&wv[0] = *(const float4*)&wrow[0];
                    *(float4*)&wv[4] = *(const float4*)&wrow[4];
#pragma unroll
                    for (int j = 0; j < 8; ++j)
#pragma unroll
                        for (int k = 0; k < 8; ++k)
                            acc[j][k] = fmaf(wv[j], av[k + kx], acc[j][k]);
                }
            }
        }
        __syncthreads();
    }
#pragma unroll
    for (int j = 0; j < 8; ++j) {
        int co = co0 + j;
        float s = sc[co], bb2 = bi[co];
        float r[8];
#pragma unroll
        for (int k = 0; k < 8; ++k) {
            float yv = fmaf(acc[j][k], s, bb2);
            r[k] = yv / (1.f + expf(-yv));
        }
        float* op = out + (size_t)(b * 256 + co) * 4096 + y * 64 + x0;
        *(float4*)&op[0] = *(float4*)&r[0];
        *(float4*)&op[4] = *(float4*)&r[4];
    }
}

// ---------------- final: Wf3 1x1 + bf3, v_add, l2norm (in-place on d_out) ----------------
__global__ __launch_bounds__(256) void final_kernel(const float* vin, const float* __restrict__ img,
                                                    const float* __restrict__ wT3,
                                                    const float* __restrict__ bf3,
                                                    const float* __restrict__ addw, float* out) {
    __shared__ float act[32 * 64];
    __shared__ float wl[32 * 256];
    __shared__ float pr[32 * 64];
    __shared__ float invs[64];
    int blk = blockIdx.x;
    int b = blk >> 6, y = blk & 63;
    int t = threadIdx.x;
    int xt = t & 7, ct = t >> 3;
    int x0 = xt * 8, co0 = ct * 8;
    const float* inb = vin + (size_t)b * 1048576 + y * 64;
    float acc[8][8];
#pragma unroll
    for (int j = 0; j < 8; ++j)
#pragma unroll
        for (int k = 0; k < 8; ++k) acc[j][k] = 0.f;

    for (int c0 = 0; c0 < 256; c0 += 32) {
#pragma unroll
        for (int j = 0; j < 8; ++j) {
            int e = t + j * 256;
            int ci = e >> 6, x = e & 63;
            act[e] = inb[(size_t)(c0 + ci) * 4096 + x];
        }
        const float* wp = wT3 + (size_t)c0 * 256;
#pragma unroll
        for (int j = 0; j < 32; ++j) wl[t + j * 256] = wp[t + j * 256];
        __syncthreads();
#pragma unroll 4
        for (int i = 0; i < 32; ++i) {
            float av[8], wv[8];
            *(float4*)&av[0] = *(const float4*)&act[i * 64 + x0];
            *(float4*)&av[4] = *(const float4*)&act[i * 64 + x0 + 4];
            *(float4*)&wv[0] = *(const float4*)&wl[i * 256 + co0];
            *(float4*)&wv[4] = *(const float4*)&wl[i * 256 + co0 + 4];
#pragma unroll
            for (int j = 0; j < 8; ++j)
#pragma unroll
                for (int k = 0; k < 8; ++k) acc[j][k] = fmaf(wv[j], av[k], acc[j][k]);
        }
        __syncthreads();
    }
    float aw = tanhf(addw[0]);
    float ps[8];
#pragma unroll
    for (int k = 0; k < 8; ++k) ps[k] = 0.f;
#pragma unroll
    for (int j = 0; j < 8; ++j) {
        int co = co0 + j;
        float b3 = bf3[co];
        const float* ip = img + (size_t)(b * 256 + co) * 4096 + y * 64 + x0;
        float ivv[8];
        *(float4*)&ivv[0] = *(const float4*)&ip[0];
        *(float4*)&ivv[4] = *(const float4*)&ip[4];
#pragma unroll
        for (int k = 0; k < 8; ++k) {
            float v = (1.f + aw) * ivv[k] + (1.f - aw) * (acc[j][k] + b3);
            acc[j][k] = v;
            ps[k] += v * v;
        }
    }
#pragma unroll
    for (int k = 0; k < 8; ++k) pr[ct * 64 + x0 + k] = ps[k];
    __syncthreads();
    if (t < 64) {
        float s2 = 0.f;
        for (int q = 0; q < 32; ++q) s2 += pr[q * 64 + t];
        invs[t] = 1.f / fmaxf(sqrtf(s2), 1e-12f);
    }
    __syncthreads();
#pragma unroll
    for (int j = 0; j < 8; ++j) {
        int co = co0 + j;
        float r[8];
#pragma unroll
        for (int k = 0; k < 8; ++k) r[k] = acc[j][k] * invs[x0 + k];
        float* op = out + (size_t)(b * 256 + co) * 4096 + y * 64 + x0;
        *(float4*)&op[0] = *(float4*)&r[0];
        *(float4*)&op[4] = *(float4*)&r[4];
    }
}

// ---------------- launch ----------------
extern "C" void kernel_launch(void* const* d_in, const int* in_sizes, int n_in,
                              void* d_out, int out_size, void* d_ws, size_t ws_size,
                              hipStream_t stream) {
    const float* img     = (const float*)d_in[0];
    const float* flang   = (const float*)d_in[1];
    const int*   wmask   = (const int*)d_in[2];
    const float* sigma_w = (const float*)d_in[3];
    const float* W1      = (const float*)d_in[4];
    const float* b1      = (const float*)d_in[5];
    const float* W2      = (const float*)d_in[6];
    const float* b2      = (const float*)d_in[7];
    const float* Wv      = (const float*)d_in[8];
    const float* sv      = (const float*)d_in[9];
    const float* bv      = (const float*)d_in[10];
    const float* Wg      = (const float*)d_in[11];
    const float* sg      = (const float*)d_in[12];
    const float* bg      = (const float*)d_in[13];
    const float* Wb      = (const float*)d_in[14];
    const float* sb      = (const float*)d_in[15];
    const float* bb      = (const float*)d_in[16];
    const float* Wf1     = (const float*)d_in[17];
    const float* sf1     = (const float*)d_in[18];
    const float* bf1     = (const float*)d_in[19];
    const float* Wf2     = (const float*)d_in[20];
    const float* sf2     = (const float*)d_in[21];
    const float* bf2     = (const float*)d_in[22];
    const float* Wf3     = (const float*)d_in[23];
    const float* bf3     = (const float*)d_in[24];
    const float* Ws      = (const float*)d_in[25];
    const float* bs      = (const float*)d_in[26];
    const float* addw    = (const float*)d_in[27];
    float* out = (float*)d_out;
    float* ws  = (float*)d_ws;

    // workspace layout (floats)
    float* WvT  = ws;                 // 65536
    float* WT1  = ws + 65536;         // 65536
    float* WT3  = ws + 131072;        // 65536
    float* WT2  = ws + 196608;        // 589824
    float* fa   = ws + 786432;        // 12288
    float* ycxc = ws + 798720;        // 256
    float* S    = ws + 798976;        // 36864
    float* sigw = ws + 835840;        // 128
    float* gmap = ws + 835968;        // 65536
    float* bmap = ws + 901504;        // 65536
    float* buf0 = ws + 967040;        // 16777216

    prep_kernel<<<2560, 256, 0, stream>>>(Wv, Wf1, Wf3, Wf2, WvT, WT1, WT3, WT2);
    lang_kernel<<<16, 256, 0, stream>>>(flang, wmask, fa);
    mlp_kernel<<<16, 448, 0, stream>>>(fa, W1, b1, W2, b2, ycxc);
    wsum_kernel<<<4096, 256, 0, stream>>>(img, S);
    sigw_kernel<<<16, 256, 0, stream>>>(Ws, S, bs, sigw);
    gauss_kernel<<<1024, 64, 0, stream>>>(ycxc, sigw, sigma_w, Wg, sg, bg, Wb, sb, bb, gmap, bmap);
    conv1x1_kernel<1><<<1024, 256, 0, stream>>>(img, WvT, sv, bv, buf0);       // map_visu
    film_kernel<<<1024, 256, 0, stream>>>(buf0, gmap, bmap, out);              // l2norm(g*mv+bmax)
    conv1x1_kernel<0><<<1024, 256, 0, stream>>>(out, WT1, sf1, bf1, buf0);     // cbs Wf1
    conv3x3_kernel<<<1024, 256, 0, stream>>>(buf0, WT2, sf2, bf2, out);        // cbs Wf2
    final_kernel<<<1024, 256, 0, stream>>>(out, img, WT3, bf3, addw, out);     // Wf3 + add + l2norm
}

// Round 2
// 817.181 us; speedup vs baseline: 1.9362x; 1.9362x over previous
//
#include <hip/hip_runtime.h>
#include <hip/hip_bf16.h>

// Problem: B=16, C=256, H=64, L=40, TD=768, NC=8, EMB=392
// R2: 3x3 conv -> bf16 MFMA implicit GEMM (M=x, N=co, K=ci*9taps).
//     f1-1x1 conv now emits NHWC bf16 for transpose-free LDS staging.
//     map_visu stored bf16 NCHW (film reads bf16) to keep ws footprint.

#define DEVFN static __device__ __forceinline__

DEVFN float sigmoidf_(float x) { return 1.f / (1.f + expf(-x)); }
DEVFN float siluf_(float y) { return y / (1.f + expf(-y)); }

typedef __attribute__((ext_vector_type(8))) short bf16x8;
typedef __attribute__((ext_vector_type(4))) float f32x4;

DEVFN unsigned short f2bf_(float f) {
    union { __hip_bfloat16 b; unsigned short u; } cv;
    cv.b = __float2bfloat16(f);
    return cv.u;
}

// ---------------- prep: weight transposes + bf16 MFMA pack for Wf2 ----------------
// WvT/WT1/WT3: [ci][co] fp32 (256x256).
// WB (bf16): B-fragment order for mfma_f32_16x16x32_bf16:
//   idx = (((kk*8 + ci32)*16 + coT)*64 + lane)*8 + j
//   value = Wf2[co=coT*16+(lane&15)][ci=ci32*32+(lane>>4)*8+j][kk]
__global__ void prep_kernel(const float* __restrict__ Wv, const float* __restrict__ Wf1,
                            const float* __restrict__ Wf3, const float* __restrict__ Wf2,
                            float* __restrict__ WvT, float* __restrict__ WT1,
                            float* __restrict__ WT3, short* __restrict__ WB) {
    int idx = blockIdx.x * 256 + threadIdx.x;
    if (idx < 65536) {
        int ci = idx >> 8, co = idx & 255;
        int src = co * 256 + ci;
        WvT[idx] = Wv[src];
        WT1[idx] = Wf1[src];
        WT3[idx] = Wf3[src];
    }
    int o = idx - 65536;
    if (o >= 0 && o < 589824) {
        int j    = o & 7;
        int lane = (o >> 3) & 63;
        int coT  = (o >> 9) & 15;
        int ci32 = (o >> 13) & 7;
        int kk   = o >> 16;
        int co = coT * 16 + (lane & 15);
        int ci = ci32 * 32 + ((lane >> 4) << 3) + j;
        WB[o] = (short)f2bf_(Wf2[(co * 256 + ci) * 9 + kk]);
    }
}

// ---------------- lang average ----------------
__global__ void lang_kernel(const float* __restrict__ flang, const int* __restrict__ mask,
                            float* __restrict__ fa) {
    __shared__ float inc[40];
    __shared__ float isum;
    int b = blockIdx.x, t = threadIdx.x;
    if (t == 0) {
        float cum[40];
        float c = 0.f;
        for (int l = 0; l < 40; ++l) { c += (float)mask[b * 40 + l]; cum[l] = c; }
        float tot = c, s = 0.f;
        for (int l = 0; l < 40; ++l) {
            float m = (float)mask[b * 40 + l];
            float v = (cum[l] > 1.f && cum[l] < tot) ? m : 0.f;
            inc[l] = v; s += v;
        }
        isum = s;
    }
    __syncthreads();
    for (int d = t; d < 768; d += 256) {
        float a = 0.f;
        for (int l = 0; l < 40; ++l) a += flang[(size_t)(b * 40 + l) * 768 + d] * inc[l];
        fa[b * 768 + d] = a / isum;
    }
}

// ---------------- lang MLP -> yc/xc ----------------
__global__ void mlp_kernel(const float* __restrict__ fa_g, const float* __restrict__ W1,
                           const float* __restrict__ b1, const float* __restrict__ W2,
                           const float* __restrict__ b2, float* __restrict__ ycxc) {
    __shared__ float fa[768];
    __shared__ float h[392];
    __shared__ float o[16];
    int b = blockIdx.x, t = threadIdx.x;
    for (int k = t; k < 768; k += 448) fa[k] = fa_g[b * 768 + k];
    __syncthreads();
    if (t < 392) {
        float a = b1[t];
        const float* w = W1 + (size_t)t * 768;
        for (int k = 0; k < 768; ++k) a = fmaf(fa[k], w[k], a);
        h[t] = a;
    }
    __syncthreads();
    if (t < 16) {
        float a = b2[t];
        const float* w = W2 + (size_t)t * 392;
        for (int k = 0; k < 392; ++k) a = fmaf(h[k], w[k], a);
        o[t] = sigmoidf_(a);
    }
    __syncthreads();
    if (t < 8) {
        ycxc[b * 8 + t]       = (float)(int)(o[2 * t] * 64.f);
        ycxc[128 + b * 8 + t] = (float)(int)(o[2 * t + 1] * 64.f);
    }
}

// ---------------- window sums for sigma (valid conv mean trick) ----------------
__global__ void wsum_kernel(const float* __restrict__ img, float* __restrict__ S) {
    __shared__ float red[9 * 256];
    int bc = blockIdx.x;            // b*256 + ci
    int t = threadIdx.x;
    float s[9];
#pragma unroll
    for (int k = 0; k < 9; ++k) s[k] = 0.f;
    const float* p = img + (size_t)bc * 4096;
    for (int j = 0; j < 16; ++j) {
        int idx = t + j * 256;
        int y = idx >> 6, x = idx & 63;
        float v = p[idx];
#pragma unroll
        for (int ky = 0; ky < 3; ++ky) {
            if (y < ky || y > ky + 61) continue;
#pragma unroll
            for (int kx = 0; kx < 3; ++kx) {
                if (x < kx || x > kx + 61) continue;
                s[ky * 3 + kx] += v;
            }
        }
    }
#pragma unroll
    for (int k = 0; k < 9; ++k) red[k * 256 + t] = s[k];
    __syncthreads();
    for (int st = 128; st > 0; st >>= 1) {
        if (t < st) {
#pragma unroll
            for (int k = 0; k < 9; ++k) red[k * 256 + t] += red[k * 256 + t + st];
        }
        __syncthreads();
    }
    if (t < 9) S[(size_t)bc * 9 + t] = red[t * 256];
}

__global__ void sigw_kernel(const float* __restrict__ Ws, const float* __restrict__ S,
                            const float* __restrict__ bs, float* __restrict__ sigw) {
    __shared__ float red[8 * 256];
    int b = blockIdx.x, t = threadIdx.x;    // t = ci
    float sv[9];
    const float* Sp = S + (size_t)(b * 256 + t) * 9;
#pragma unroll
    for (int k = 0; k < 9; ++k) sv[k] = Sp[k];
#pragma unroll
    for (int co = 0; co < 8; ++co) {
        const float* wp = Ws + (size_t)(co * 256 + t) * 9;
        float a = 0.f;
#pragma unroll
        for (int k = 0; k < 9; ++k) a = fmaf(wp[k], sv[k], a);
        red[co * 256 + t] = a;
    }
    __syncthreads();
    for (int st = 128; st > 0; st >>= 1) {
        if (t < st) {
#pragma unroll
            for (int co = 0; co < 8; ++co) red[co * 256 + t] += red[co * 256 + t + st];
        }
        __syncthreads();
    }
    if (t < 8) sigw[b * 8 + t] = sigmoidf_(red[t * 256] / 3844.f + bs[t]);
}

// ---------------- gaussian -> gamma/beta -> g, bmax ----------------
__global__ void gauss_kernel(const float* __restrict__ ycxc, const float* __restrict__ sigw,
                             const float* __restrict__ sigma_w,
                             const float* __restrict__ Wg, const float* __restrict__ sg,
                             const float* __restrict__ bg,
                             const float* __restrict__ Wb, const float* __restrict__ sb,
                             const float* __restrict__ bb,
                             float* __restrict__ g, float* __restrict__ bm) {
    int blk = blockIdx.x;
    int b = blk >> 6, y = blk & 63;
    int x = threadIdx.x;
    float sx = sigma_w[0] * 64.f;
    float w[8];
#pragma unroll
    for (int n = 0; n < 8; ++n) {
        float yc = ycxc[b * 8 + n], xc = ycxc[128 + b * 8 + n];
        float sy = sx * sigw[b * 8 + n];
        float dy = (float)y - yc, dx = (float)x - xc;
        w[n] = expf(-(dy * dy / (2.f * sy * sy) + dx * dx / (2.f * sx * sx)));
    }
    float gacc = 0.f, bmax = -3.4e38f;
#pragma unroll
    for (int n = 0; n < 8; ++n) {
        float a1 = 0.f, a2 = 0.f;
#pragma unroll
        for (int m = 0; m < 8; ++m) {
            a1 = fmaf(Wg[n * 8 + m], w[m], a1);
            a2 = fmaf(Wb[n * 8 + m], w[m], a2);
        }
        float ga = tanhf(siluf_(a1 * sg[n] + bg[n]));
        float be = tanhf(siluf_(a2 * sb[n] + bb[n]));
        gacc += ga;
        bmax = fmaxf(bmax, be);
    }
    g[(size_t)(b * 64 + y) * 64 + x] = gacc * 0.125f;
    bm[(size_t)(b * 64 + y) * 64 + x] = bmax;
}

// ---------------- 1x1 conv 256->256 fp32 VALU, bf16 output ----------------
// MODE 1: tanh(silu) -> NCHW bf16 (map_visu). MODE 0: silu -> NHWC bf16 (f1).
template <int MODE>
__global__ __launch_bounds__(256) void conv1x1_kernel(const float* __restrict__ in,
                                                      const float* __restrict__ wT,
                                                      const float* __restrict__ sc,
                                                      const float* __restrict__ bi,
                                                      __hip_bfloat16* __restrict__ outb) {
    __shared__ float act[32 * 64];     // [ci][x]
    __shared__ float wl[32 * 256];     // [ci][co]
    int blk = blockIdx.x;
    int b = blk >> 6, y = blk & 63;
    int t = threadIdx.x;
    int xt = t & 7, ct = t >> 3;
    int x0 = xt * 8, co0 = ct * 8;
    const float* inb = in + (size_t)b * 1048576 + y * 64;
    float acc[8][8];
#pragma unroll
    for (int j = 0; j < 8; ++j)
#pragma unroll
        for (int k = 0; k < 8; ++k) acc[j][k] = 0.f;

    for (int c0 = 0; c0 < 256; c0 += 32) {
#pragma unroll
        for (int j = 0; j < 8; ++j) {
            int e = t + j * 256;
            int ci = e >> 6, x = e & 63;
            act[e] = inb[(size_t)(c0 + ci) * 4096 + x];
        }
        const float* wp = wT + (size_t)c0 * 256;
#pragma unroll
        for (int j = 0; j < 32; ++j) wl[t + j * 256] = wp[t + j * 256];
        __syncthreads();
#pragma unroll 4
        for (int i = 0; i < 32; ++i) {
            float av[8], wv[8];
            *(float4*)&av[0] = *(const float4*)&act[i * 64 + x0];
            *(float4*)&av[4] = *(const float4*)&act[i * 64 + x0 + 4];
            *(float4*)&wv[0] = *(const float4*)&wl[i * 256 + co0];
            *(float4*)&wv[4] = *(const float4*)&wl[i * 256 + co0 + 4];
#pragma unroll
            for (int j = 0; j < 8; ++j)
#pragma unroll
                for (int k = 0; k < 8; ++k) acc[j][k] = fmaf(wv[j], av[k], acc[j][k]);
        }
        __syncthreads();
    }
    float s8[8], b8[8];
#pragma unroll
    for (int j = 0; j < 8; ++j) { s8[j] = sc[co0 + j]; b8[j] = bi[co0 + j]; }
    if (MODE == 1) {
        // tanh(silu) -> NCHW bf16
#pragma unroll
        for (int j = 0; j < 8; ++j) {
            unsigned short r[8];
#pragma unroll
            for (int k = 0; k < 8; ++k) {
                float yv = fmaf(acc[j][k], s8[j], b8[j]);
                r[k] = f2bf_(tanhf(siluf_(yv)));
            }
            unsigned short* op = (unsigned short*)outb + (size_t)(b * 256 + co0 + j) * 4096 + y * 64 + x0;
            *(uint4*)op = *(uint4*)r;
        }
    } else {
        // silu -> NHWC bf16
#pragma unroll
        for (int k = 0; k < 8; ++k) {
            unsigned short r[8];
#pragma unroll
            for (int j = 0; j < 8; ++j) {
                float yv = fmaf(acc[j][k], s8[j], b8[j]);
                r[j] = f2bf_(siluf_(yv));
            }
            unsigned short* op = (unsigned short*)outb + ((size_t)(b * 64 + y) * 64 + x0 + k) * 256 + co0;
            *(uint4*)op = *(uint4*)r;
        }
    }
}

// ---------------- film: v = l2norm(g*mv + bmax), mv is bf16 NCHW ----------------
__global__ __launch_bounds__(256) void film_kernel(const __hip_bfloat16* __restrict__ mv,
                                                   const float* __restrict__ g,
                                                   const float* __restrict__ bm,
                                                   float* __restrict__ out) {
    __shared__ float pr[4 * 64];
    __shared__ float invs[64];
    int blk = blockIdx.x;
    int b = blk >> 6, y = blk & 63;
    int t = threadIdx.x;
    int x = t & 63, cg = t >> 6;
    float gv = g[(size_t)(b * 64 + y) * 64 + x];
    float bv = bm[(size_t)(b * 64 + y) * 64 + x];
    const __hip_bfloat16* mp = mv + (size_t)b * 1048576 + y * 64 + x;
    float ss = 0.f;
    for (int co = cg; co < 256; co += 4) {
        float v = fmaf(gv, __bfloat162float(mp[(size_t)co * 4096]), bv);
        ss += v * v;
    }
    pr[cg * 64 + x] = ss;
    __syncthreads();
    if (t < 64)
        invs[t] = 1.f / fmaxf(sqrtf(pr[t] + pr[64 + t] + pr[128 + t] + pr[192 + t]), 1e-12f);
    __syncthreads();
    float iv = invs[x];
    float* op = out + (size_t)b * 1048576 + y * 64 + x;
    for (int co = cg; co < 256; co += 4) {
        float v = fmaf(gv, __bfloat162float(mp[(size_t)co * 4096]), bv);
        op[(size_t)co * 4096] = v * iv;
    }
}

// ---------------- 3x3 conv 256->256 pad1 + silu : bf16 MFMA ----------------
// Input NHWC bf16. One block per (b,y): M=64 x, N=256 co, K=2304.
// LDS: 3 rows x 66 xp x 64 ci (chunked), x-stride padded to 72 shorts (144B).
__global__ __launch_bounds__(256, 3) void conv3x3_mfma(const __hip_bfloat16* __restrict__ xin,
                                                       const short* __restrict__ wb,
                                                       const float* __restrict__ sc,
                                                       const float* __restrict__ bi,
                                                       float* __restrict__ out) {
    __shared__ short lds[3 * 66 * 72];      // 28512 B
    int blk = blockIdx.x;
    int b = blk >> 6, y = blk & 63;
    int t = threadIdx.x;
    int w = t >> 6, lane = t & 63;
    int lx = lane & 15, koct = lane >> 4;
    const unsigned short* xg = (const unsigned short*)xin + (size_t)b * 1048576;

    f32x4 acc[4][4];
#pragma unroll
    for (int mi = 0; mi < 4; ++mi)
#pragma unroll
        for (int ni = 0; ni < 4; ++ni) acc[mi][ni] = (f32x4){0.f, 0.f, 0.f, 0.f};

    for (int cc = 0; cc < 4; ++cc) {        // ci chunks of 64
        __syncthreads();
#pragma unroll
        for (int p = 0; p < 7; ++p) {
            int u = t + p * 256;
            if (u < 1584) {                 // 3 rows * 66 xp * 8 ci8-units
                int r = u / 528;
                int rem = u - r * 528;
                int xp = rem >> 3, ci8 = rem & 7;
                int ys = y + r - 1, xs = xp - 1;
                uint4 v = {0u, 0u, 0u, 0u};
                if (ys >= 0 && ys < 64 && xs >= 0 && xs < 64)
                    v = *(const uint4*)(xg + ((size_t)(ys * 64 + xs) * 256 + cc * 64 + ci8 * 8));
                *(uint4*)&lds[(r * 66 + xp) * 72 + ci8 * 8] = v;
            }
        }
        __syncthreads();
        for (int kk = 0; kk < 9; ++kk) {
            int ky = kk / 3, kx = kk - ky * 3;
#pragma unroll
            for (int k32 = 0; k32 < 2; ++k32) {
                int ci32g = cc * 2 + k32;
                const short* wp = wb + ((((kk * 8 + ci32g) * 16) + w * 4) * 64 + lane) * 8;
                bf16x8 bfr[4];
#pragma unroll
                for (int ni = 0; ni < 4; ++ni)
                    bfr[ni] = *(const bf16x8*)(wp + ni * 512);
                bf16x8 afr[4];
#pragma unroll
                for (int mi = 0; mi < 4; ++mi)
                    afr[mi] = *(const bf16x8*)&lds[(ky * 66 + mi * 16 + lx + kx) * 72 + k32 * 32 + koct * 8];
#pragma unroll
                for (int mi = 0; mi < 4; ++mi)
#pragma unroll
                    for (int ni = 0; ni < 4; ++ni)
                        acc[mi][ni] = __builtin_amdgcn_mfma_f32_16x16x32_bf16(afr[mi], bfr[ni], acc[mi][ni], 0, 0, 0);
            }
        }
    }
    // epilogue: y = acc*sc+bi ; silu ; fp32 NCHW store
#pragma unroll
    for (int ni = 0; ni < 4; ++ni) {
        int co = w * 64 + ni * 16 + lx;
        float s = sc[co], bb2 = bi[co];
        float* ob = out + ((size_t)(b * 256 + co) * 64 + y) * 64;
#pragma unroll
        for (int mi = 0; mi < 4; ++mi) {
            float r[4];
#pragma unroll
            for (int rr = 0; rr < 4; ++rr) {
                float yv = fmaf(acc[mi][ni][rr], s, bb2);
                r[rr] = siluf_(yv);
            }
            *(float4*)&ob[mi * 16 + koct * 4] = *(float4*)r;
        }
    }
}

// ---------------- final: Wf3 1x1 + bf3, v_add, l2norm (in-place on d_out) ----------------
__global__ __launch_bounds__(256) void final_kernel(const float* vin, const float* __restrict__ img,
                                                    const float* __restrict__ wT3,
                                                    const float* __restrict__ bf3,
                                                    const float* __restrict__ addw, float* out) {
    __shared__ float act[32 * 64];
    __shared__ float wl[32 * 256];
    __shared__ float pr[32 * 64];
    __shared__ float invs[64];
    int blk = blockIdx.x;
    int b = blk >> 6, y = blk & 63;
    int t = threadIdx.x;
    int xt = t & 7, ct = t >> 3;
    int x0 = xt * 8, co0 = ct * 8;
    const float* inb = vin + (size_t)b * 1048576 + y * 64;
    float acc[8][8];
#pragma unroll
    for (int j = 0; j < 8; ++j)
#pragma unroll
        for (int k = 0; k < 8; ++k) acc[j][k] = 0.f;

    for (int c0 = 0; c0 < 256; c0 += 32) {
#pragma unroll
        for (int j = 0; j < 8; ++j) {
            int e = t + j * 256;
            int ci = e >> 6, x = e & 63;
            act[e] = inb[(size_t)(c0 + ci) * 4096 + x];
        }
        const float* wp = wT3 + (size_t)c0 * 256;
#pragma unroll
        for (int j = 0; j < 32; ++j) wl[t + j * 256] = wp[t + j * 256];
        __syncthreads();
#pragma unroll 4
        for (int i = 0; i < 32; ++i) {
            float av[8], wv[8];
            *(float4*)&av[0] = *(const float4*)&act[i * 64 + x0];
            *(float4*)&av[4] = *(const float4*)&act[i * 64 + x0 + 4];
            *(float4*)&wv[0] = *(const float4*)&wl[i * 256 + co0];
            *(float4*)&wv[4] = *(const float4*)&wl[i * 256 + co0 + 4];
#pragma unroll
            for (int j = 0; j < 8; ++j)
#pragma unroll
                for (int k = 0; k < 8; ++k) acc[j][k] = fmaf(wv[j], av[k], acc[j][k]);
        }
        __syncthreads();
    }
    float aw = tanhf(addw[0]);
    float ps[8];
#pragma unroll
    for (int k = 0; k < 8; ++k) ps[k] = 0.f;
#pragma unroll
    for (int j = 0; j < 8; ++j) {
        int co = co0 + j;
        float b3 = bf3[co];
        const float* ip = img + (size_t)(b * 256 + co) * 4096 + y * 64 + x0;
        float ivv[8];
        *(float4*)&ivv[0] = *(const float4*)&ip[0];
        *(float4*)&ivv[4] = *(const float4*)&ip[4];
#pragma unroll
        for (int k = 0; k < 8; ++k) {
            float v = (1.f + aw) * ivv[k] + (1.f - aw) * (acc[j][k] + b3);
            acc[j][k] = v;
            ps[k] += v * v;
        }
    }
#pragma unroll
    for (int k = 0; k < 8; ++k) pr[ct * 64 + x0 + k] = ps[k];
    __syncthreads();
    if (t < 64) {
        float s2 = 0.f;
        for (int q = 0; q < 32; ++q) s2 += pr[q * 64 + t];
        invs[t] = 1.f / fmaxf(sqrtf(s2), 1e-12f);
    }
    __syncthreads();
#pragma unroll
    for (int j = 0; j < 8; ++j) {
        int co = co0 + j;
        float r[8];
#pragma unroll
        for (int k = 0; k < 8; ++k) r[k] = acc[j][k] * invs[x0 + k];
        float* op = out + (size_t)(b * 256 + co) * 4096 + y * 64 + x0;
        *(float4*)&op[0] = *(float4*)&r[0];
        *(float4*)&op[4] = *(float4*)&r[4];
    }
}

// ---------------- launch ----------------
extern "C" void kernel_launch(void* const* d_in, const int* in_sizes, int n_in,
                              void* d_out, int out_size, void* d_ws, size_t ws_size,
                              hipStream_t stream) {
    const float* img     = (const float*)d_in[0];
    const float* flang   = (const float*)d_in[1];
    const int*   wmask   = (const int*)d_in[2];
    const float* sigma_w = (const float*)d_in[3];
    const float* W1      = (const float*)d_in[4];
    const float* b1      = (const float*)d_in[5];
    const float* W2      = (const float*)d_in[6];
    const float* b2      = (const float*)d_in[7];
    const float* Wv      = (const float*)d_in[8];
    const float* sv      = (const float*)d_in[9];
    const float* bv      = (const float*)d_in[10];
    const float* Wg      = (const float*)d_in[11];
    const float* sg      = (const float*)d_in[12];
    const float* bg      = (const float*)d_in[13];
    const float* Wb      = (const float*)d_in[14];
    const float* sb      = (const float*)d_in[15];
    const float* bb      = (const float*)d_in[16];
    const float* Wf1     = (const float*)d_in[17];
    const float* sf1     = (const float*)d_in[18];
    const float* bf1     = (const float*)d_in[19];
    const float* Wf2     = (const float*)d_in[20];
    const float* sf2     = (const float*)d_in[21];
    const float* bf2     = (const float*)d_in[22];
    const float* Wf3     = (const float*)d_in[23];
    const float* bf3     = (const float*)d_in[24];
    const float* Ws      = (const float*)d_in[25];
    const float* bs      = (const float*)d_in[26];
    const float* addw    = (const float*)d_in[27];
    float* out = (float*)d_out;
    float* ws  = (float*)d_ws;

    // workspace layout (float offsets)
    float* WvT  = ws;                       // 65536
    float* WT1  = ws + 65536;               // 65536
    float* WT3  = ws + 131072;              // 65536
    short* WB   = (short*)(ws + 196608);    // 589824 shorts = 294912 floats
    float* fa   = ws + 491520;              // 12288
    float* ycxc = ws + 503808;              // 256
    float* S    = ws + 504064;              // 36864
    float* sigw = ws + 540928;              // 128
    float* gmap = ws + 541056;              // 65536
    float* bmap = ws + 606592;              // 65536
    __hip_bfloat16* mvis  = (__hip_bfloat16*)(ws + 672128);   // 16.78M bf16 (NCHW)
    __hip_bfloat16* f1out = (__hip_bfloat16*)(ws + 9060736);  // 16.78M bf16 (NHWC)
    // ends at float offset 17449344 (~69.8 MB)

    prep_kernel<<<2560, 256, 0, stream>>>(Wv, Wf1, Wf3, Wf2, WvT, WT1, WT3, WB);
    lang_kernel<<<16, 256, 0, stream>>>(flang, wmask, fa);
    mlp_kernel<<<16, 448, 0, stream>>>(fa, W1, b1, W2, b2, ycxc);
    wsum_kernel<<<4096, 256, 0, stream>>>(img, S);
    sigw_kernel<<<16, 256, 0, stream>>>(Ws, S, bs, sigw);
    gauss_kernel<<<1024, 64, 0, stream>>>(ycxc, sigw, sigma_w, Wg, sg, bg, Wb, sb, bb, gmap, bmap);
    conv1x1_kernel<1><<<1024, 256, 0, stream>>>(img, WvT, sv, bv, mvis);       // map_visu (bf16 NCHW)
    film_kernel<<<1024, 256, 0, stream>>>(mvis, gmap, bmap, out);              // l2norm(g*mv+bmax) fp32
    conv1x1_kernel<0><<<1024, 256, 0, stream>>>(out, WT1, sf1, bf1, f1out);    // cbs Wf1 -> NHWC bf16
    conv3x3_mfma<<<1024, 256, 0, stream>>>(f1out, WB, sf2, bf2, out);          // cbs Wf2 (MFMA)
    final_kernel<<<1024, 256, 0, stream>>>(out, img, WT3, bf3, addw, out);     // Wf3 + add + l2norm
}

// Round 3
// 465.693 us; speedup vs baseline: 3.3975x; 1.7548x over previous
//
#include <hip/hip_runtime.h>
#include <hip/hip_bf16.h>

// Problem: B=16, C=256, H=64, L=40, TD=768, NC=8, EMB=392
// R3: all four C x C convs on MFMA. mfma1x1<MODE> fuses:
//   MODE 0: Wv 1x1 + tanh(silu) + FiLM(g,bmax) + l2norm -> bf16 NHWC
//   MODE 1: Wf1 1x1 + silu -> bf16 NHWC
//   MODE 2: Wf3 1x1 + bf3 + v_add(img) + l2norm -> fp32 NCHW (d_out)
// conv3x3_mfma emits bf16 NHWC via LDS restage.

#define DEVFN static __device__ __forceinline__

DEVFN float sigmoidf_(float x) { return 1.f / (1.f + expf(-x)); }
DEVFN float siluf_(float y) { return y / (1.f + expf(-y)); }

typedef __attribute__((ext_vector_type(8))) short bf16x8;
typedef __attribute__((ext_vector_type(4))) float f32x4;

DEVFN unsigned short f2bf_(float f) {
    union { __hip_bfloat16 b; unsigned short u; } cv;
    cv.b = __float2bfloat16(f);
    return cv.u;
}

// ---------------- prep: pack all conv weights into MFMA B-fragment order ----------------
// 1-tap (WvB/W1B/W3B): idx = ((ci32*16 + coT)*64 + lane)*8 + j
//   value = W[co=coT*16+(lane&15)][ci=ci32*32+(lane>>4)*8+j]
// 9-tap (WB2): idx = (((kk*8 + ci32)*16 + coT)*64 + lane)*8 + j
__global__ void prep_kernel(const float* __restrict__ Wv, const float* __restrict__ Wf1,
                            const float* __restrict__ Wf3, const float* __restrict__ Wf2,
                            short* __restrict__ WvB, short* __restrict__ W1B,
                            short* __restrict__ W3B, short* __restrict__ WB2) {
    int idx = blockIdx.x * 256 + threadIdx.x;
    if (idx < 65536) {
        int j    = idx & 7;
        int lane = (idx >> 3) & 63;
        int coT  = (idx >> 9) & 15;
        int ci32 = (idx >> 13) & 7;
        int co = coT * 16 + (lane & 15);
        int ci = ci32 * 32 + ((lane >> 4) << 3) + j;
        int src = co * 256 + ci;
        WvB[idx] = (short)f2bf_(Wv[src]);
        W1B[idx] = (short)f2bf_(Wf1[src]);
        W3B[idx] = (short)f2bf_(Wf3[src]);
    }
    int o = idx - 65536;
    if (o >= 0 && o < 589824) {
        int j    = o & 7;
        int lane = (o >> 3) & 63;
        int coT  = (o >> 9) & 15;
        int ci32 = (o >> 13) & 7;
        int kk   = o >> 16;
        int co = coT * 16 + (lane & 15);
        int ci = ci32 * 32 + ((lane >> 4) << 3) + j;
        WB2[o] = (short)f2bf_(Wf2[(co * 256 + ci) * 9 + kk]);
    }
}

// ---------------- lang average ----------------
__global__ void lang_kernel(const float* __restrict__ flang, const int* __restrict__ mask,
                            float* __restrict__ fa) {
    __shared__ float inc[40];
    __shared__ float isum;
    int b = blockIdx.x, t = threadIdx.x;
    if (t == 0) {
        float cum[40];
        float c = 0.f;
        for (int l = 0; l < 40; ++l) { c += (float)mask[b * 40 + l]; cum[l] = c; }
        float tot = c, s = 0.f;
        for (int l = 0; l < 40; ++l) {
            float m = (float)mask[b * 40 + l];
            float v = (cum[l] > 1.f && cum[l] < tot) ? m : 0.f;
            inc[l] = v; s += v;
        }
        isum = s;
    }
    __syncthreads();
    for (int d = t; d < 768; d += 256) {
        float a = 0.f;
        for (int l = 0; l < 40; ++l) a += flang[(size_t)(b * 40 + l) * 768 + d] * inc[l];
        fa[b * 768 + d] = a / isum;
    }
}

// ---------------- lang MLP -> yc/xc ----------------
__global__ void mlp_kernel(const float* __restrict__ fa_g, const float* __restrict__ W1,
                           const float* __restrict__ b1, const float* __restrict__ W2,
                           const float* __restrict__ b2, float* __restrict__ ycxc) {
    __shared__ float fa[768];
    __shared__ float h[392];
    __shared__ float o[16];
    int b = blockIdx.x, t = threadIdx.x;
    for (int k = t; k < 768; k += 448) fa[k] = fa_g[b * 768 + k];
    __syncthreads();
    if (t < 392) {
        float a = b1[t];
        const float* w = W1 + (size_t)t * 768;
        for (int k = 0; k < 768; ++k) a = fmaf(fa[k], w[k], a);
        h[t] = a;
    }
    __syncthreads();
    if (t < 16) {
        float a = b2[t];
        const float* w = W2 + (size_t)t * 392;
        for (int k = 0; k < 392; ++k) a = fmaf(h[k], w[k], a);
        o[t] = sigmoidf_(a);
    }
    __syncthreads();
    if (t < 8) {
        ycxc[b * 8 + t]       = (float)(int)(o[2 * t] * 64.f);
        ycxc[128 + b * 8 + t] = (float)(int)(o[2 * t + 1] * 64.f);
    }
}

// ---------------- window sums for sigma (valid conv mean trick) ----------------
__global__ void wsum_kernel(const float* __restrict__ img, float* __restrict__ S) {
    __shared__ float red[9 * 256];
    int bc = blockIdx.x;            // b*256 + ci
    int t = threadIdx.x;
    float s[9];
#pragma unroll
    for (int k = 0; k < 9; ++k) s[k] = 0.f;
    const float* p = img + (size_t)bc * 4096;
    for (int j = 0; j < 16; ++j) {
        int idx = t + j * 256;
        int y = idx >> 6, x = idx & 63;
        float v = p[idx];
#pragma unroll
        for (int ky = 0; ky < 3; ++ky) {
            if (y < ky || y > ky + 61) continue;
#pragma unroll
            for (int kx = 0; kx < 3; ++kx) {
                if (x < kx || x > kx + 61) continue;
                s[ky * 3 + kx] += v;
            }
        }
    }
#pragma unroll
    for (int k = 0; k < 9; ++k) red[k * 256 + t] = s[k];
    __syncthreads();
    for (int st = 128; st > 0; st >>= 1) {
        if (t < st) {
#pragma unroll
            for (int k = 0; k < 9; ++k) red[k * 256 + t] += red[k * 256 + t + st];
        }
        __syncthreads();
    }
    if (t < 9) S[(size_t)bc * 9 + t] = red[t * 256];
}

__global__ void sigw_kernel(const float* __restrict__ Ws, const float* __restrict__ S,
                            const float* __restrict__ bs, float* __restrict__ sigw) {
    __shared__ float red[8 * 256];
    int b = blockIdx.x, t = threadIdx.x;    // t = ci
    float sv[9];
    const float* Sp = S + (size_t)(b * 256 + t) * 9;
#pragma unroll
    for (int k = 0; k < 9; ++k) sv[k] = Sp[k];
#pragma unroll
    for (int co = 0; co < 8; ++co) {
        const float* wp = Ws + (size_t)(co * 256 + t) * 9;
        float a = 0.f;
#pragma unroll
        for (int k = 0; k < 9; ++k) a = fmaf(wp[k], sv[k], a);
        red[co * 256 + t] = a;
    }
    __syncthreads();
    for (int st = 128; st > 0; st >>= 1) {
        if (t < st) {
#pragma unroll
            for (int co = 0; co < 8; ++co) red[co * 256 + t] += red[co * 256 + t + st];
        }
        __syncthreads();
    }
    if (t < 8) sigw[b * 8 + t] = sigmoidf_(red[t * 256] / 3844.f + bs[t]);
}

// ---------------- gaussian -> gamma/beta -> g, bmax ----------------
__global__ void gauss_kernel(const float* __restrict__ ycxc, const float* __restrict__ sigw,
                             const float* __restrict__ sigma_w,
                             const float* __restrict__ Wg, const float* __restrict__ sg,
                             const float* __restrict__ bg,
                             const float* __restrict__ Wb, const float* __restrict__ sb,
                             const float* __restrict__ bb,
                             float* __restrict__ g, float* __restrict__ bm) {
    int blk = blockIdx.x;
    int b = blk >> 6, y = blk & 63;
    int x = threadIdx.x;
    float sx = sigma_w[0] * 64.f;
    float w[8];
#pragma unroll
    for (int n = 0; n < 8; ++n) {
        float yc = ycxc[b * 8 + n], xc = ycxc[128 + b * 8 + n];
        float sy = sx * sigw[b * 8 + n];
        float dy = (float)y - yc, dx = (float)x - xc;
        w[n] = expf(-(dy * dy / (2.f * sy * sy) + dx * dx / (2.f * sx * sx)));
    }
    float gacc = 0.f, bmax = -3.4e38f;
#pragma unroll
    for (int n = 0; n < 8; ++n) {
        float a1 = 0.f, a2 = 0.f;
#pragma unroll
        for (int m = 0; m < 8; ++m) {
            a1 = fmaf(Wg[n * 8 + m], w[m], a1);
            a2 = fmaf(Wb[n * 8 + m], w[m], a2);
        }
        float ga = tanhf(siluf_(a1 * sg[n] + bg[n]));
        float be = tanhf(siluf_(a2 * sb[n] + bb[n]));
        gacc += ga;
        bmax = fmaxf(bmax, be);
    }
    g[(size_t)(b * 64 + y) * 64 + x] = gacc * 0.125f;
    bm[(size_t)(b * 64 + y) * 64 + x] = bmax;
}

// ---------------- MFMA 1x1 conv 256->256, fused epilogues ----------------
// Block per (b,y). M=64 x, N=256 co (wave w -> co block w*64), K=256 ci.
template <int MODE>
__global__ __launch_bounds__(256) void mfma1x1(
        const float* __restrict__ inF,            // MODE0: img NCHW fp32
        const __hip_bfloat16* __restrict__ inB,   // MODE1/2: NHWC bf16
        const short* __restrict__ wb,
        const float* __restrict__ sc, const float* __restrict__ bi,
        const float* __restrict__ g, const float* __restrict__ bm,
        const float* __restrict__ img, const float* __restrict__ addw,
        __hip_bfloat16* __restrict__ outB, float* __restrict__ outF) {
    __shared__ __attribute__((aligned(16))) short lA[64 * 264];   // 33792 B
    __shared__ float ls_s[256], ls_b[256];
    __shared__ float ls_g[64], ls_bm[64];
    int blk = blockIdx.x, b = blk >> 6, y = blk & 63;
    int t = threadIdx.x, w = t >> 6, lane = t & 63;
    int lx = lane & 15, koct = lane >> 4;

    if (MODE != 2) { ls_s[t] = sc[t]; }
    ls_b[t] = bi[t];
    if (MODE == 0 && t < 64) {
        ls_g[t]  = g[(size_t)(b * 64 + y) * 64 + t];
        ls_bm[t] = bm[(size_t)(b * 64 + y) * 64 + t];
    }

    // ---- stage A into LDS [x][ci], x-stride 264 shorts ----
    if (MODE == 0) {
        int x = t & 63, cg = t >> 6;
        const float* ib = inF + (size_t)b * 1048576 + y * 64 + x;
#pragma unroll
        for (int c8 = 0; c8 < 8; ++c8) {
            int ci0 = cg * 64 + c8 * 8;
            unsigned short r[8];
#pragma unroll
            for (int j = 0; j < 8; ++j) r[j] = f2bf_(ib[(size_t)(ci0 + j) * 4096]);
            *(uint4*)&lA[x * 264 + ci0] = *(uint4*)r;
        }
    } else {
        const unsigned short* xg = (const unsigned short*)inB + (size_t)(b * 64 + y) * 16384;
#pragma unroll
        for (int it = 0; it < 8; ++it) {
            int e8 = t + it * 256;
            int x2 = e8 >> 5, c8 = e8 & 31;
            *(uint4*)&lA[x2 * 264 + c8 * 8] = *(const uint4*)(xg + e8 * 8);
        }
    }

    f32x4 acc[4][4];
#pragma unroll
    for (int mi = 0; mi < 4; ++mi)
#pragma unroll
        for (int ni = 0; ni < 4; ++ni) acc[mi][ni] = (f32x4){0.f, 0.f, 0.f, 0.f};
    __syncthreads();

#pragma unroll
    for (int k32 = 0; k32 < 8; ++k32) {
        const short* wp = wb + (((k32 * 16) + w * 4) * 64 + lane) * 8;
        bf16x8 bfr[4];
#pragma unroll
        for (int ni = 0; ni < 4; ++ni) bfr[ni] = *(const bf16x8*)(wp + ni * 512);
        bf16x8 afr[4];
#pragma unroll
        for (int mi = 0; mi < 4; ++mi)
            afr[mi] = *(const bf16x8*)&lA[(mi * 16 + lx) * 264 + k32 * 32 + koct * 8];
#pragma unroll
        for (int mi = 0; mi < 4; ++mi)
#pragma unroll
            for (int ni = 0; ni < 4; ++ni)
                acc[mi][ni] = __builtin_amdgcn_mfma_f32_16x16x32_bf16(afr[mi], bfr[ni], acc[mi][ni], 0, 0, 0);
    }

    if constexpr (MODE == 0) {
        // mv = tanh(silu(acc*s+b)); v = g*mv + bmax; l2norm over co; bf16 NHWC out
        __shared__ float pr[4096];
        __shared__ float invs[64];
#pragma unroll
        for (int mi = 0; mi < 4; ++mi)
#pragma unroll
            for (int rr = 0; rr < 4; ++rr) {
                int x = mi * 16 + koct * 4 + rr;
                float ps = 0.f;
#pragma unroll
                for (int ni = 0; ni < 4; ++ni) {
                    int co = w * 64 + ni * 16 + lx;
                    float yv = fmaf(acc[mi][ni][rr], ls_s[co], ls_b[co]);
                    float mvv = tanhf(siluf_(yv));
                    float v = fmaf(ls_g[x], mvv, ls_bm[x]);
                    acc[mi][ni][rr] = v;
                    ps += v * v;
                }
                pr[x * 64 + w * 16 + lx] = ps;
            }
        __syncthreads();
        if (t < 64) {
            float s2 = 0.f;
            for (int q = 0; q < 64; ++q) s2 += pr[t * 64 + q];
            invs[t] = 1.f / fmaxf(sqrtf(s2), 1e-12f);
        }
        __syncthreads();
#pragma unroll
        for (int mi = 0; mi < 4; ++mi)
#pragma unroll
            for (int ni = 0; ni < 4; ++ni) {
                int co = w * 64 + ni * 16 + lx;
#pragma unroll
                for (int rr = 0; rr < 4; ++rr) {
                    int x = mi * 16 + koct * 4 + rr;
                    lA[x * 264 + co] = (short)f2bf_(acc[mi][ni][rr] * invs[x]);
                }
            }
        __syncthreads();
        unsigned short* og = (unsigned short*)outB + (size_t)(b * 64 + y) * 16384;
#pragma unroll
        for (int it = 0; it < 8; ++it) {
            int e8 = t + it * 256;
            int x2 = e8 >> 5, c8 = e8 & 31;
            *(uint4*)(og + e8 * 8) = *(uint4*)&lA[x2 * 264 + c8 * 8];
        }
    } else if constexpr (MODE == 1) {
        // silu(acc*s+b) -> bf16 NHWC
        __syncthreads();
#pragma unroll
        for (int mi = 0; mi < 4; ++mi)
#pragma unroll
            for (int ni = 0; ni < 4; ++ni) {
                int co = w * 64 + ni * 16 + lx;
#pragma unroll
                for (int rr = 0; rr < 4; ++rr) {
                    int x = mi * 16 + koct * 4 + rr;
                    float yv = fmaf(acc[mi][ni][rr], ls_s[co], ls_b[co]);
                    lA[x * 264 + co] = (short)f2bf_(siluf_(yv));
                }
            }
        __syncthreads();
        unsigned short* og = (unsigned short*)outB + (size_t)(b * 64 + y) * 16384;
#pragma unroll
        for (int it = 0; it < 8; ++it) {
            int e8 = t + it * 256;
            int x2 = e8 >> 5, c8 = e8 & 31;
            *(uint4*)(og + e8 * 8) = *(uint4*)&lA[x2 * 264 + c8 * 8];
        }
    } else {
        // v = (1+aw)*img + (1-aw)*(acc + bf3); l2norm over co; fp32 NCHW out
        __shared__ float pr[4096];
        __shared__ float invs[64];
        float aw = tanhf(addw[0]);
#pragma unroll
        for (int mi = 0; mi < 4; ++mi)
#pragma unroll
            for (int ni = 0; ni < 4; ++ni) {
                int co = w * 64 + ni * 16 + lx;
                const float* ip = img + ((size_t)(b * 256 + co) * 64 + y) * 64 + mi * 16 + koct * 4;
                float4 im = *(const float4*)ip;
                float imv[4] = {im.x, im.y, im.z, im.w};
#pragma unroll
                for (int rr = 0; rr < 4; ++rr) {
                    float v = (1.f + aw) * imv[rr] + (1.f - aw) * (acc[mi][ni][rr] + ls_b[co]);
                    acc[mi][ni][rr] = v;
                }
            }
#pragma unroll
        for (int mi = 0; mi < 4; ++mi)
#pragma unroll
            for (int rr = 0; rr < 4; ++rr) {
                int x = mi * 16 + koct * 4 + rr;
                float ps = 0.f;
#pragma unroll
                for (int ni = 0; ni < 4; ++ni) ps += acc[mi][ni][rr] * acc[mi][ni][rr];
                pr[x * 64 + w * 16 + lx] = ps;
            }
        __syncthreads();
        if (t < 64) {
            float s2 = 0.f;
            for (int q = 0; q < 64; ++q) s2 += pr[t * 64 + q];
            invs[t] = 1.f / fmaxf(sqrtf(s2), 1e-12f);
        }
        __syncthreads();
#pragma unroll
        for (int mi = 0; mi < 4; ++mi)
#pragma unroll
            for (int ni = 0; ni < 4; ++ni) {
                int co = w * 64 + ni * 16 + lx;
                float r[4];
#pragma unroll
                for (int rr = 0; rr < 4; ++rr) {
                    int x = mi * 16 + koct * 4 + rr;
                    r[rr] = acc[mi][ni][rr] * invs[x];
                }
                float* op = outF + ((size_t)(b * 256 + co) * 64 + y) * 64 + mi * 16 + koct * 4;
                *(float4*)op = *(float4*)r;
            }
    }
}

// ---------------- 3x3 conv 256->256 pad1 + silu : bf16 MFMA, bf16 NHWC out ----------------
__global__ __launch_bounds__(256, 3) void conv3x3_mfma(const __hip_bfloat16* __restrict__ xin,
                                                       const short* __restrict__ wb,
                                                       const float* __restrict__ sc,
                                                       const float* __restrict__ bi,
                                                       __hip_bfloat16* __restrict__ outB) {
    __shared__ __attribute__((aligned(16))) short lds[64 * 264];   // staging 3*66*72=14256 fits; restage 64*264
    int blk = blockIdx.x;
    int b = blk >> 6, y = blk & 63;
    int t = threadIdx.x;
    int w = t >> 6, lane = t & 63;
    int lx = lane & 15, koct = lane >> 4;
    const unsigned short* xg = (const unsigned short*)xin + (size_t)b * 1048576;

    f32x4 acc[4][4];
#pragma unroll
    for (int mi = 0; mi < 4; ++mi)
#pragma unroll
        for (int ni = 0; ni < 4; ++ni) acc[mi][ni] = (f32x4){0.f, 0.f, 0.f, 0.f};

    for (int cc = 0; cc < 4; ++cc) {        // ci chunks of 64
        __syncthreads();
#pragma unroll
        for (int p = 0; p < 7; ++p) {
            int u = t + p * 256;
            if (u < 1584) {                 // 3 rows * 66 xp * 8 ci8-units
                int r = u / 528;
                int rem = u - r * 528;
                int xp = rem >> 3, ci8 = rem & 7;
                int ys = y + r - 1, xs = xp - 1;
                uint4 v = {0u, 0u, 0u, 0u};
                if (ys >= 0 && ys < 64 && xs >= 0 && xs < 64)
                    v = *(const uint4*)(xg + ((size_t)(ys * 64 + xs) * 256 + cc * 64 + ci8 * 8));
                *(uint4*)&lds[(r * 66 + xp) * 72 + ci8 * 8] = v;
            }
        }
        __syncthreads();
        for (int kk = 0; kk < 9; ++kk) {
            int ky = kk / 3, kx = kk - ky * 3;
#pragma unroll
            for (int k32 = 0; k32 < 2; ++k32) {
                int ci32g = cc * 2 + k32;
                const short* wp = wb + ((((kk * 8 + ci32g) * 16) + w * 4) * 64 + lane) * 8;
                bf16x8 bfr[4];
#pragma unroll
                for (int ni = 0; ni < 4; ++ni)
                    bfr[ni] = *(const bf16x8*)(wp + ni * 512);
                bf16x8 afr[4];
#pragma unroll
                for (int mi = 0; mi < 4; ++mi)
                    afr[mi] = *(const bf16x8*)&lds[(ky * 66 + mi * 16 + lx + kx) * 72 + k32 * 32 + koct * 8];
#pragma unroll
                for (int mi = 0; mi < 4; ++mi)
#pragma unroll
                    for (int ni = 0; ni < 4; ++ni)
                        acc[mi][ni] = __builtin_amdgcn_mfma_f32_16x16x32_bf16(afr[mi], bfr[ni], acc[mi][ni], 0, 0, 0);
            }
        }
    }
    // epilogue: silu(acc*sc+bi) -> bf16 NHWC via LDS restage
    __syncthreads();
#pragma unroll
    for (int ni = 0; ni < 4; ++ni) {
        int co = w * 64 + ni * 16 + lx;
        float s = sc[co], bb2 = bi[co];
#pragma unroll
        for (int mi = 0; mi < 4; ++mi)
#pragma unroll
            for (int rr = 0; rr < 4; ++rr) {
                int x = mi * 16 + koct * 4 + rr;
                float yv = fmaf(acc[mi][ni][rr], s, bb2);
                lds[x * 264 + co] = (short)f2bf_(siluf_(yv));
            }
    }
    __syncthreads();
    unsigned short* og = (unsigned short*)outB + (size_t)(b * 64 + y) * 16384;
#pragma unroll
    for (int it = 0; it < 8; ++it) {
        int e8 = t + it * 256;
        int x2 = e8 >> 5, c8 = e8 & 31;
        *(uint4*)(og + e8 * 8) = *(uint4*)&lds[x2 * 264 + c8 * 8];
    }
}

// ---------------- launch ----------------
extern "C" void kernel_launch(void* const* d_in, const int* in_sizes, int n_in,
                              void* d_out, int out_size, void* d_ws, size_t ws_size,
                              hipStream_t stream) {
    const float* img     = (const float*)d_in[0];
    const float* flang   = (const float*)d_in[1];
    const int*   wmask   = (const int*)d_in[2];
    const float* sigma_w = (const float*)d_in[3];
    const float* W1      = (const float*)d_in[4];
    const float* b1      = (const float*)d_in[5];
    const float* W2      = (const float*)d_in[6];
    const float* b2      = (const float*)d_in[7];
    const float* Wv      = (const float*)d_in[8];
    const float* sv      = (const float*)d_in[9];
    const float* bv      = (const float*)d_in[10];
    const float* Wg      = (const float*)d_in[11];
    const float* sg      = (const float*)d_in[12];
    const float* bg      = (const float*)d_in[13];
    const float* Wb      = (const float*)d_in[14];
    const float* sb      = (const float*)d_in[15];
    const float* bb      = (const float*)d_in[16];
    const float* Wf1     = (const float*)d_in[17];
    const float* sf1     = (const float*)d_in[18];
    const float* bf1     = (const float*)d_in[19];
    const float* Wf2     = (const float*)d_in[20];
    const float* sf2     = (const float*)d_in[21];
    const float* bf2     = (const float*)d_in[22];
    const float* Wf3     = (const float*)d_in[23];
    const float* bf3     = (const float*)d_in[24];
    const float* Ws      = (const float*)d_in[25];
    const float* bs      = (const float*)d_in[26];
    const float* addw    = (const float*)d_in[27];
    float* out = (float*)d_out;
    float* ws  = (float*)d_ws;

    // workspace layout (float offsets)
    short* WvB  = (short*)ws;                     // 65536 shorts = 32768 f
    short* W1B  = (short*)(ws + 32768);           // 32768 f
    short* W3B  = (short*)(ws + 65536);           // 32768 f
    short* WB2  = (short*)(ws + 98304);           // 589824 shorts = 294912 f
    float* fa   = ws + 393216;                    // 12288
    float* ycxc = ws + 405504;                    // 256
    float* S    = ws + 405760;                    // 36864
    float* sigw = ws + 442624;                    // 128
    float* gmap = ws + 442752;                    // 65536
    float* bmap = ws + 508288;                    // 65536
    __hip_bfloat16* bufA = (__hip_bfloat16*)(ws + 573824);   // 16.78M bf16 NHWC
    __hip_bfloat16* bufB = (__hip_bfloat16*)(ws + 8962432);  // 16.78M bf16 NHWC
    // ends at float offset 17351040 (~69.4 MB)

    prep_kernel<<<2560, 256, 0, stream>>>(Wv, Wf1, Wf3, Wf2, WvB, W1B, W3B, WB2);
    lang_kernel<<<16, 256, 0, stream>>>(flang, wmask, fa);
    mlp_kernel<<<16, 448, 0, stream>>>(fa, W1, b1, W2, b2, ycxc);
    wsum_kernel<<<4096, 256, 0, stream>>>(img, S);
    sigw_kernel<<<16, 256, 0, stream>>>(Ws, S, bs, sigw);
    gauss_kernel<<<1024, 64, 0, stream>>>(ycxc, sigw, sigma_w, Wg, sg, bg, Wb, sb, bb, gmap, bmap);
    // v = l2norm(g*tanh(silu(Wv*img*sv+bv)) + bmax)  -> bufA (bf16 NHWC)
    mfma1x1<0><<<1024, 256, 0, stream>>>(img, nullptr, WvB, sv, bv, gmap, bmap,
                                         nullptr, nullptr, bufA, nullptr);
    // f1 = silu(Wf1*v*sf1+bf1) -> bufB (bf16 NHWC)
    mfma1x1<1><<<1024, 256, 0, stream>>>(nullptr, bufA, W1B, sf1, bf1, nullptr, nullptr,
                                         nullptr, nullptr, bufB, nullptr);
    // f2 = silu(Wf2(3x3)*f1*sf2+bf2) -> bufA (bf16 NHWC)
    conv3x3_mfma<<<1024, 256, 0, stream>>>(bufB, WB2, sf2, bf2, bufA);
    // out = l2norm((1+aw)*img + (1-aw)*(Wf3*f2 + bf3)) -> d_out (fp32 NCHW)
    mfma1x1<2><<<1024, 256, 0, stream>>>(nullptr, bufA, W3B, nullptr, bf3, nullptr, nullptr,
                                         img, addw, nullptr, out);
}

// Round 4
// 429.979 us; speedup vs baseline: 3.6797x; 1.0831x over previous
//
#include <hip/hip_runtime.h>
#include <hip/hip_bf16.h>

// Problem: B=16, C=256, H=64, L=40, TD=768, NC=8, EMB=392
// R4: f01_kernel fuses Wv-1x1 + tanh/silu + FiLM + l2norm + Wf1-1x1 + silu
//     (two chained MFMA GEMMs through LDS). conv3x3 v2: 2-row M=128 tile,
//     halved B-fragment traffic and halo refetch. pr scratch aliased onto
//     dead A-tile LDS in f01/final for occupancy.

#define DEVFN static __device__ __forceinline__

DEVFN float sigmoidf_(float x) { return 1.f / (1.f + expf(-x)); }
DEVFN float siluf_(float y) { return y / (1.f + expf(-y)); }

typedef __attribute__((ext_vector_type(8))) short bf16x8;
typedef __attribute__((ext_vector_type(4))) float f32x4;

DEVFN unsigned short f2bf_(float f) {
    union { __hip_bfloat16 b; unsigned short u; } cv;
    cv.b = __float2bfloat16(f);
    return cv.u;
}

// ---------------- prep: pack all conv weights into MFMA B-fragment order ----------------
// 1-tap (WvB/W1B/W3B): idx = ((ci32*16 + coT)*64 + lane)*8 + j
// 9-tap (WB2): idx = (((kk*8 + ci32)*16 + coT)*64 + lane)*8 + j
__global__ void prep_kernel(const float* __restrict__ Wv, const float* __restrict__ Wf1,
                            const float* __restrict__ Wf3, const float* __restrict__ Wf2,
                            short* __restrict__ WvB, short* __restrict__ W1B,
                            short* __restrict__ W3B, short* __restrict__ WB2) {
    int idx = blockIdx.x * 256 + threadIdx.x;
    if (idx < 65536) {
        int j    = idx & 7;
        int lane = (idx >> 3) & 63;
        int coT  = (idx >> 9) & 15;
        int ci32 = (idx >> 13) & 7;
        int co = coT * 16 + (lane & 15);
        int ci = ci32 * 32 + ((lane >> 4) << 3) + j;
        int src = co * 256 + ci;
        WvB[idx] = (short)f2bf_(Wv[src]);
        W1B[idx] = (short)f2bf_(Wf1[src]);
        W3B[idx] = (short)f2bf_(Wf3[src]);
    }
    int o = idx - 65536;
    if (o >= 0 && o < 589824) {
        int j    = o & 7;
        int lane = (o >> 3) & 63;
        int coT  = (o >> 9) & 15;
        int ci32 = (o >> 13) & 7;
        int kk   = o >> 16;
        int co = coT * 16 + (lane & 15);
        int ci = ci32 * 32 + ((lane >> 4) << 3) + j;
        WB2[o] = (short)f2bf_(Wf2[(co * 256 + ci) * 9 + kk]);
    }
}

// ---------------- lang average ----------------
__global__ void lang_kernel(const float* __restrict__ flang, const int* __restrict__ mask,
                            float* __restrict__ fa) {
    __shared__ float inc[40];
    __shared__ float isum;
    int b = blockIdx.x, t = threadIdx.x;
    if (t == 0) {
        float cum[40];
        float c = 0.f;
        for (int l = 0; l < 40; ++l) { c += (float)mask[b * 40 + l]; cum[l] = c; }
        float tot = c, s = 0.f;
        for (int l = 0; l < 40; ++l) {
            float m = (float)mask[b * 40 + l];
            float v = (cum[l] > 1.f && cum[l] < tot) ? m : 0.f;
            inc[l] = v; s += v;
        }
        isum = s;
    }
    __syncthreads();
    for (int d = t; d < 768; d += 256) {
        float a = 0.f;
        for (int l = 0; l < 40; ++l) a += flang[(size_t)(b * 40 + l) * 768 + d] * inc[l];
        fa[b * 768 + d] = a / isum;
    }
}

// ---------------- lang MLP -> yc/xc ----------------
__global__ void mlp_kernel(const float* __restrict__ fa_g, const float* __restrict__ W1,
                           const float* __restrict__ b1, const float* __restrict__ W2,
                           const float* __restrict__ b2, float* __restrict__ ycxc) {
    __shared__ float fa[768];
    __shared__ float h[392];
    __shared__ float o[16];
    int b = blockIdx.x, t = threadIdx.x;
    for (int k = t; k < 768; k += 448) fa[k] = fa_g[b * 768 + k];
    __syncthreads();
    if (t < 392) {
        float a = b1[t];
        const float* w = W1 + (size_t)t * 768;
        for (int k = 0; k < 768; ++k) a = fmaf(fa[k], w[k], a);
        h[t] = a;
    }
    __syncthreads();
    if (t < 16) {
        float a = b2[t];
        const float* w = W2 + (size_t)t * 392;
        for (int k = 0; k < 392; ++k) a = fmaf(h[k], w[k], a);
        o[t] = sigmoidf_(a);
    }
    __syncthreads();
    if (t < 8) {
        ycxc[b * 8 + t]       = (float)(int)(o[2 * t] * 64.f);
        ycxc[128 + b * 8 + t] = (float)(int)(o[2 * t + 1] * 64.f);
    }
}

// ---------------- window sums for sigma (valid conv mean trick) ----------------
__global__ void wsum_kernel(const float* __restrict__ img, float* __restrict__ S) {
    __shared__ float red[9 * 256];
    int bc = blockIdx.x;            // b*256 + ci
    int t = threadIdx.x;
    float s[9];
#pragma unroll
    for (int k = 0; k < 9; ++k) s[k] = 0.f;
    const float* p = img + (size_t)bc * 4096;
    for (int j = 0; j < 16; ++j) {
        int idx = t + j * 256;
        int y = idx >> 6, x = idx & 63;
        float v = p[idx];
#pragma unroll
        for (int ky = 0; ky < 3; ++ky) {
            if (y < ky || y > ky + 61) continue;
#pragma unroll
            for (int kx = 0; kx < 3; ++kx) {
                if (x < kx || x > kx + 61) continue;
                s[ky * 3 + kx] += v;
            }
        }
    }
#pragma unroll
    for (int k = 0; k < 9; ++k) red[k * 256 + t] = s[k];
    __syncthreads();
    for (int st = 128; st > 0; st >>= 1) {
        if (t < st) {
#pragma unroll
            for (int k = 0; k < 9; ++k) red[k * 256 + t] += red[k * 256 + t + st];
        }
        __syncthreads();
    }
    if (t < 9) S[(size_t)bc * 9 + t] = red[t * 256];
}

__global__ void sigw_kernel(const float* __restrict__ Ws, const float* __restrict__ S,
                            const float* __restrict__ bs, float* __restrict__ sigw) {
    __shared__ float red[8 * 256];
    int b = blockIdx.x, t = threadIdx.x;    // t = ci
    float sv[9];
    const float* Sp = S + (size_t)(b * 256 + t) * 9;
#pragma unroll
    for (int k = 0; k < 9; ++k) sv[k] = Sp[k];
#pragma unroll
    for (int co = 0; co < 8; ++co) {
        const float* wp = Ws + (size_t)(co * 256 + t) * 9;
        float a = 0.f;
#pragma unroll
        for (int k = 0; k < 9; ++k) a = fmaf(wp[k], sv[k], a);
        red[co * 256 + t] = a;
    }
    __syncthreads();
    for (int st = 128; st > 0; st >>= 1) {
        if (t < st) {
#pragma unroll
            for (int co = 0; co < 8; ++co) red[co * 256 + t] += red[co * 256 + t + st];
        }
        __syncthreads();
    }
    if (t < 8) sigw[b * 8 + t] = sigmoidf_(red[t * 256] / 3844.f + bs[t]);
}

// ---------------- gaussian -> gamma/beta -> g, bmax ----------------
__global__ void gauss_kernel(const float* __restrict__ ycxc, const float* __restrict__ sigw,
                             const float* __restrict__ sigma_w,
                             const float* __restrict__ Wg, const float* __restrict__ sg,
                             const float* __restrict__ bg,
                             const float* __restrict__ Wb, const float* __restrict__ sb,
                             const float* __restrict__ bb,
                             float* __restrict__ g, float* __restrict__ bm) {
    int blk = blockIdx.x;
    int b = blk >> 6, y = blk & 63;
    int x = threadIdx.x;
    float sx = sigma_w[0] * 64.f;
    float w[8];
#pragma unroll
    for (int n = 0; n < 8; ++n) {
        float yc = ycxc[b * 8 + n], xc = ycxc[128 + b * 8 + n];
        float sy = sx * sigw[b * 8 + n];
        float dy = (float)y - yc, dx = (float)x - xc;
        w[n] = expf(-(dy * dy / (2.f * sy * sy) + dx * dx / (2.f * sx * sx)));
    }
    float gacc = 0.f, bmax = -3.4e38f;
#pragma unroll
    for (int n = 0; n < 8; ++n) {
        float a1 = 0.f, a2 = 0.f;
#pragma unroll
        for (int m = 0; m < 8; ++m) {
            a1 = fmaf(Wg[n * 8 + m], w[m], a1);
            a2 = fmaf(Wb[n * 8 + m], w[m], a2);
        }
        float ga = tanhf(siluf_(a1 * sg[n] + bg[n]));
        float be = tanhf(siluf_(a2 * sb[n] + bb[n]));
        gacc += ga;
        bmax = fmaxf(bmax, be);
    }
    g[(size_t)(b * 64 + y) * 64 + x] = gacc * 0.125f;
    bm[(size_t)(b * 64 + y) * 64 + x] = bmax;
}

// ---------------- fused: Wv 1x1 + tanh(silu) + FiLM + l2norm + Wf1 1x1 + silu ----------------
// Block per (b,y). Two chained GEMMs (M=64 x, N=256 co, K=256) through LDS.
// pr (l2norm partials) aliases the dead A-tile LDS.
__global__ __launch_bounds__(256) void f01_kernel(
        const float* __restrict__ img, const short* __restrict__ wvb,
        const short* __restrict__ w1b,
        const float* __restrict__ sv, const float* __restrict__ bv,
        const float* __restrict__ s1, const float* __restrict__ b1,
        const float* __restrict__ g, const float* __restrict__ bm,
        __hip_bfloat16* __restrict__ outB) {
    __shared__ __attribute__((aligned(16))) short lA[64 * 264];   // 33792 B
    __shared__ float invs[64];
    __shared__ float ls_sv[256], ls_bv[256], ls_s1[256], ls_b1[256];
    __shared__ float ls_g[64], ls_bm[64];
    float* pr = (float*)lA;                                        // alias (sequenced)
    int blk = blockIdx.x, b = blk >> 6, y = blk & 63;
    int t = threadIdx.x, w = t >> 6, lane = t & 63;
    int lx = lane & 15, koct = lane >> 4;

    ls_sv[t] = sv[t]; ls_bv[t] = bv[t];
    ls_s1[t] = s1[t]; ls_b1[t] = b1[t];
    if (t < 64) {
        ls_g[t]  = g[(size_t)(b * 64 + y) * 64 + t];
        ls_bm[t] = bm[(size_t)(b * 64 + y) * 64 + t];
    }

    // stage img (fp32 NCHW) -> lA bf16 [x][ci]
    {
        int x = t & 63, cg = t >> 6;
        const float* ib = img + (size_t)b * 1048576 + y * 64 + x;
#pragma unroll
        for (int c8 = 0; c8 < 8; ++c8) {
            int ci0 = cg * 64 + c8 * 8;
            unsigned short r[8];
#pragma unroll
            for (int j = 0; j < 8; ++j) r[j] = f2bf_(ib[(size_t)(ci0 + j) * 4096]);
            *(uint4*)&lA[x * 264 + ci0] = *(uint4*)r;
        }
    }
    f32x4 acc[4][4];
#pragma unroll
    for (int mi = 0; mi < 4; ++mi)
#pragma unroll
        for (int ni = 0; ni < 4; ++ni) acc[mi][ni] = (f32x4){0.f, 0.f, 0.f, 0.f};
    __syncthreads();

    // GEMM1: Wv
#pragma unroll
    for (int k32 = 0; k32 < 8; ++k32) {
        const short* wp = wvb + (((k32 * 16) + w * 4) * 64 + lane) * 8;
        bf16x8 bfr[4];
#pragma unroll
        for (int ni = 0; ni < 4; ++ni) bfr[ni] = *(const bf16x8*)(wp + ni * 512);
        bf16x8 afr[4];
#pragma unroll
        for (int mi = 0; mi < 4; ++mi)
            afr[mi] = *(const bf16x8*)&lA[(mi * 16 + lx) * 264 + k32 * 32 + koct * 8];
#pragma unroll
        for (int mi = 0; mi < 4; ++mi)
#pragma unroll
            for (int ni = 0; ni < 4; ++ni)
                acc[mi][ni] = __builtin_amdgcn_mfma_f32_16x16x32_bf16(afr[mi], bfr[ni], acc[mi][ni], 0, 0, 0);
    }
    __syncthreads();   // lA (img) dead; pr may now be written

    // film epilogue: mv = tanh(silu(acc*sv+bv)); v = g*mv + bmax; partial l2
#pragma unroll
    for (int mi = 0; mi < 4; ++mi)
#pragma unroll
        for (int rr = 0; rr < 4; ++rr) {
            int x = mi * 16 + koct * 4 + rr;
            float ps = 0.f;
#pragma unroll
            for (int ni = 0; ni < 4; ++ni) {
                int co = w * 64 + ni * 16 + lx;
                float yv = fmaf(acc[mi][ni][rr], ls_sv[co], ls_bv[co]);
                float mvv = tanhf(siluf_(yv));
                float v = fmaf(ls_g[x], mvv, ls_bm[x]);
                acc[mi][ni][rr] = v;
                ps += v * v;
            }
            pr[x * 64 + w * 16 + lx] = ps;
        }
    __syncthreads();
    if (t < 64) {
        float s2 = 0.f;
        for (int q = 0; q < 64; ++q) s2 += pr[t * 64 + q];
        invs[t] = 1.f / fmaxf(sqrtf(s2), 1e-12f);
    }
    __syncthreads();   // pr dead; lA may be rewritten (v)

    // v (normalized) -> lA bf16 [x][ci]
#pragma unroll
    for (int mi = 0; mi < 4; ++mi)
#pragma unroll
        for (int ni = 0; ni < 4; ++ni) {
            int co = w * 64 + ni * 16 + lx;
#pragma unroll
            for (int rr = 0; rr < 4; ++rr) {
                int x = mi * 16 + koct * 4 + rr;
                lA[x * 264 + co] = (short)f2bf_(acc[mi][ni][rr] * invs[x]);
            }
        }
#pragma unroll
    for (int mi = 0; mi < 4; ++mi)
#pragma unroll
        for (int ni = 0; ni < 4; ++ni) acc[mi][ni] = (f32x4){0.f, 0.f, 0.f, 0.f};
    __syncthreads();

    // GEMM2: Wf1
#pragma unroll
    for (int k32 = 0; k32 < 8; ++k32) {
        const short* wp = w1b + (((k32 * 16) + w * 4) * 64 + lane) * 8;
        bf16x8 bfr[4];
#pragma unroll
        for (int ni = 0; ni < 4; ++ni) bfr[ni] = *(const bf16x8*)(wp + ni * 512);
        bf16x8 afr[4];
#pragma unroll
        for (int mi = 0; mi < 4; ++mi)
            afr[mi] = *(const bf16x8*)&lA[(mi * 16 + lx) * 264 + k32 * 32 + koct * 8];
#pragma unroll
        for (int mi = 0; mi < 4; ++mi)
#pragma unroll
            for (int ni = 0; ni < 4; ++ni)
                acc[mi][ni] = __builtin_amdgcn_mfma_f32_16x16x32_bf16(afr[mi], bfr[ni], acc[mi][ni], 0, 0, 0);
    }
    __syncthreads();

    // silu -> lA [x][co] -> NHWC store
#pragma unroll
    for (int mi = 0; mi < 4; ++mi)
#pragma unroll
        for (int ni = 0; ni < 4; ++ni) {
            int co = w * 64 + ni * 16 + lx;
#pragma unroll
            for (int rr = 0; rr < 4; ++rr) {
                int x = mi * 16 + koct * 4 + rr;
                float yv = fmaf(acc[mi][ni][rr], ls_s1[co], ls_b1[co]);
                lA[x * 264 + co] = (short)f2bf_(siluf_(yv));
            }
        }
    __syncthreads();
    unsigned short* og = (unsigned short*)outB + (size_t)(b * 64 + y) * 16384;
#pragma unroll
    for (int it = 0; it < 8; ++it) {
        int e8 = t + it * 256;
        int x2 = e8 >> 5, c8 = e8 & 31;
        *(uint4*)(og + e8 * 8) = *(uint4*)&lA[x2 * 264 + c8 * 8];
    }
}

// ---------------- 3x3 conv v2: 2-row M=128 tile, bf16 MFMA, bf16 NHWC out ----------------
__global__ __launch_bounds__(256, 2) void conv3x3_mfma(const __hip_bfloat16* __restrict__ xin,
                                                       const short* __restrict__ wb,
                                                       const float* __restrict__ sc,
                                                       const float* __restrict__ bi,
                                                       __hip_bfloat16* __restrict__ outB) {
    __shared__ __attribute__((aligned(16))) short lds[4 * 66 * 72];   // 38016 B
    int blk = blockIdx.x;
    int b = blk >> 5, y0 = (blk & 31) * 2;
    int t = threadIdx.x;
    int w = t >> 6, lane = t & 63;
    int lx = lane & 15, koct = lane >> 4;
    const unsigned short* xg = (const unsigned short*)xin + (size_t)b * 1048576;

    f32x4 acc[8][4];
#pragma unroll
    for (int mi = 0; mi < 8; ++mi)
#pragma unroll
        for (int ni = 0; ni < 4; ++ni) acc[mi][ni] = (f32x4){0.f, 0.f, 0.f, 0.f};

    for (int cc = 0; cc < 4; ++cc) {        // ci chunks of 64
        __syncthreads();
#pragma unroll
        for (int p = 0; p < 9; ++p) {
            int u = t + p * 256;
            if (u < 2112) {                 // 4 rows * 66 xp * 8 ci8-units
                int r = u / 528;
                int rem = u - r * 528;
                int xp = rem >> 3, ci8 = rem & 7;
                int ys = y0 + r - 1, xs = xp - 1;
                uint4 v = {0u, 0u, 0u, 0u};
                if (ys >= 0 && ys < 64 && xs >= 0 && xs < 64)
                    v = *(const uint4*)(xg + ((size_t)(ys * 64 + xs) * 256 + cc * 64 + ci8 * 8));
                *(uint4*)&lds[(r * 66 + xp) * 72 + ci8 * 8] = v;
            }
        }
        __syncthreads();
        for (int kk = 0; kk < 9; ++kk) {
            int ky = kk / 3, kx = kk - ky * 3;
#pragma unroll
            for (int k32 = 0; k32 < 2; ++k32) {
                int ci32g = cc * 2 + k32;
                const short* wp = wb + ((((kk * 8 + ci32g) * 16) + w * 4) * 64 + lane) * 8;
                bf16x8 bfr[4];
#pragma unroll
                for (int ni = 0; ni < 4; ++ni)
                    bfr[ni] = *(const bf16x8*)(wp + ni * 512);
                bf16x8 afr[8];
#pragma unroll
                for (int mi = 0; mi < 8; ++mi) {
                    int row = mi >> 2, xb = (mi & 3) * 16;
                    afr[mi] = *(const bf16x8*)&lds[((row + ky) * 66 + xb + lx + kx) * 72 + k32 * 32 + koct * 8];
                }
#pragma unroll
                for (int mi = 0; mi < 8; ++mi)
#pragma unroll
                    for (int ni = 0; ni < 4; ++ni)
                        acc[mi][ni] = __builtin_amdgcn_mfma_f32_16x16x32_bf16(afr[mi], bfr[ni], acc[mi][ni], 0, 0, 0);
            }
        }
    }
    // epilogue: silu(acc*sc+bi) -> bf16 NHWC via LDS restage, one row at a time
#pragma unroll
    for (int r2 = 0; r2 < 2; ++r2) {
        __syncthreads();
#pragma unroll
        for (int mi4 = 0; mi4 < 4; ++mi4) {
            int mi = r2 * 4 + mi4;
#pragma unroll
            for (int ni = 0; ni < 4; ++ni) {
                int co = w * 64 + ni * 16 + lx;
                float s = sc[co], bb2 = bi[co];
#pragma unroll
                for (int rr = 0; rr < 4; ++rr) {
                    int x = mi4 * 16 + koct * 4 + rr;
                    float yv = fmaf(acc[mi][ni][rr], s, bb2);
                    lds[x * 264 + co] = (short)f2bf_(siluf_(yv));
                }
            }
        }
        __syncthreads();
        unsigned short* og = (unsigned short*)outB + (size_t)(b * 64 + y0 + r2) * 16384;
#pragma unroll
        for (int it = 0; it < 8; ++it) {
            int e8 = t + it * 256;
            int x2 = e8 >> 5, c8 = e8 & 31;
            *(uint4*)(og + e8 * 8) = *(uint4*)&lds[x2 * 264 + c8 * 8];
        }
    }
}

// ---------------- final: Wf3 1x1 + bf3, v_add, l2norm -> fp32 NCHW ----------------
__global__ __launch_bounds__(256) void final_mfma(const __hip_bfloat16* __restrict__ inB,
                                                  const short* __restrict__ w3b,
                                                  const float* __restrict__ bf3,
                                                  const float* __restrict__ img,
                                                  const float* __restrict__ addw,
                                                  float* __restrict__ outF) {
    __shared__ __attribute__((aligned(16))) short lA[64 * 264];
    __shared__ float invs[64];
    __shared__ float ls_b[256];
    float* pr = (float*)lA;     // alias (sequenced)
    int blk = blockIdx.x, b = blk >> 6, y = blk & 63;
    int t = threadIdx.x, w = t >> 6, lane = t & 63;
    int lx = lane & 15, koct = lane >> 4;
    ls_b[t] = bf3[t];

    const unsigned short* xg = (const unsigned short*)inB + (size_t)(b * 64 + y) * 16384;
#pragma unroll
    for (int it = 0; it < 8; ++it) {
        int e8 = t + it * 256;
        int x2 = e8 >> 5, c8 = e8 & 31;
        *(uint4*)&lA[x2 * 264 + c8 * 8] = *(const uint4*)(xg + e8 * 8);
    }
    f32x4 acc[4][4];
#pragma unroll
    for (int mi = 0; mi < 4; ++mi)
#pragma unroll
        for (int ni = 0; ni < 4; ++ni) acc[mi][ni] = (f32x4){0.f, 0.f, 0.f, 0.f};
    __syncthreads();

#pragma unroll
    for (int k32 = 0; k32 < 8; ++k32) {
        const short* wp = w3b + (((k32 * 16) + w * 4) * 64 + lane) * 8;
        bf16x8 bfr[4];
#pragma unroll
        for (int ni = 0; ni < 4; ++ni) bfr[ni] = *(const bf16x8*)(wp + ni * 512);
        bf16x8 afr[4];
#pragma unroll
        for (int mi = 0; mi < 4; ++mi)
            afr[mi] = *(const bf16x8*)&lA[(mi * 16 + lx) * 264 + k32 * 32 + koct * 8];
#pragma unroll
        for (int mi = 0; mi < 4; ++mi)
#pragma unroll
            for (int ni = 0; ni < 4; ++ni)
                acc[mi][ni] = __builtin_amdgcn_mfma_f32_16x16x32_bf16(afr[mi], bfr[ni], acc[mi][ni], 0, 0, 0);
    }
    __syncthreads();   // lA dead; pr writable

    float aw = tanhf(addw[0]);
#pragma unroll
    for (int mi = 0; mi < 4; ++mi)
#pragma unroll
        for (int ni = 0; ni < 4; ++ni) {
            int co = w * 64 + ni * 16 + lx;
            const float* ip = img + ((size_t)(b * 256 + co) * 64 + y) * 64 + mi * 16 + koct * 4;
            float4 im = *(const float4*)ip;
            float imv[4] = {im.x, im.y, im.z, im.w};
#pragma unroll
            for (int rr = 0; rr < 4; ++rr) {
                float v = (1.f + aw) * imv[rr] + (1.f - aw) * (acc[mi][ni][rr] + ls_b[co]);
                acc[mi][ni][rr] = v;
            }
        }
#pragma unroll
    for (int mi = 0; mi < 4; ++mi)
#pragma unroll
        for (int rr = 0; rr < 4; ++rr) {
            int x = mi * 16 + koct * 4 + rr;
            float ps = 0.f;
#pragma unroll
            for (int ni = 0; ni < 4; ++ni) ps += acc[mi][ni][rr] * acc[mi][ni][rr];
            pr[x * 64 + w * 16 + lx] = ps;
        }
    __syncthreads();
    if (t < 64) {
        float s2 = 0.f;
        for (int q = 0; q < 64; ++q) s2 += pr[t * 64 + q];
        invs[t] = 1.f / fmaxf(sqrtf(s2), 1e-12f);
    }
    __syncthreads();
#pragma unroll
    for (int mi = 0; mi < 4; ++mi)
#pragma unroll
        for (int ni = 0; ni < 4; ++ni) {
            int co = w * 64 + ni * 16 + lx;
            float r[4];
#pragma unroll
            for (int rr = 0; rr < 4; ++rr) {
                int x = mi * 16 + koct * 4 + rr;
                r[rr] = acc[mi][ni][rr] * invs[x];
            }
            float* op = outF + ((size_t)(b * 256 + co) * 64 + y) * 64 + mi * 16 + koct * 4;
            *(float4*)op = *(float4*)r;
        }
}

// ---------------- launch ----------------
extern "C" void kernel_launch(void* const* d_in, const int* in_sizes, int n_in,
                              void* d_out, int out_size, void* d_ws, size_t ws_size,
                              hipStream_t stream) {
    const float* img     = (const float*)d_in[0];
    const float* flang   = (const float*)d_in[1];
    const int*   wmask   = (const int*)d_in[2];
    const float* sigma_w = (const float*)d_in[3];
    const float* W1      = (const float*)d_in[4];
    const float* b1      = (const float*)d_in[5];
    const float* W2      = (const float*)d_in[6];
    const float* b2      = (const float*)d_in[7];
    const float* Wv      = (const float*)d_in[8];
    const float* sv      = (const float*)d_in[9];
    const float* bv      = (const float*)d_in[10];
    const float* Wg      = (const float*)d_in[11];
    const float* sg      = (const float*)d_in[12];
    const float* bg      = (const float*)d_in[13];
    const float* Wb      = (const float*)d_in[14];
    const float* sb      = (const float*)d_in[15];
    const float* bb      = (const float*)d_in[16];
    const float* Wf1     = (const float*)d_in[17];
    const float* sf1     = (const float*)d_in[18];
    const float* bf1     = (const float*)d_in[19];
    const float* Wf2     = (const float*)d_in[20];
    const float* sf2     = (const float*)d_in[21];
    const float* bf2     = (const float*)d_in[22];
    const float* Wf3     = (const float*)d_in[23];
    const float* bf3     = (const float*)d_in[24];
    const float* Ws      = (const float*)d_in[25];
    const float* bs      = (const float*)d_in[26];
    const float* addw    = (const float*)d_in[27];
    float* out = (float*)d_out;
    float* ws  = (float*)d_ws;

    // workspace layout (float offsets)
    short* WvB  = (short*)ws;                     // 32768 f
    short* W1B  = (short*)(ws + 32768);           // 32768 f
    short* W3B  = (short*)(ws + 65536);           // 32768 f
    short* WB2  = (short*)(ws + 98304);           // 294912 f
    float* fa   = ws + 393216;                    // 12288
    float* ycxc = ws + 405504;                    // 256
    float* S    = ws + 405760;                    // 36864
    float* sigw = ws + 442624;                    // 128
    float* gmap = ws + 442752;                    // 65536
    float* bmap = ws + 508288;                    // 65536
    __hip_bfloat16* bufA = (__hip_bfloat16*)(ws + 573824);   // 16.78M bf16 NHWC
    __hip_bfloat16* bufB = (__hip_bfloat16*)(ws + 8962432);  // 16.78M bf16 NHWC

    prep_kernel<<<2560, 256, 0, stream>>>(Wv, Wf1, Wf3, Wf2, WvB, W1B, W3B, WB2);
    lang_kernel<<<16, 256, 0, stream>>>(flang, wmask, fa);
    mlp_kernel<<<16, 448, 0, stream>>>(fa, W1, b1, W2, b2, ycxc);
    wsum_kernel<<<4096, 256, 0, stream>>>(img, S);
    sigw_kernel<<<16, 256, 0, stream>>>(Ws, S, bs, sigw);
    gauss_kernel<<<1024, 64, 0, stream>>>(ycxc, sigw, sigma_w, Wg, sg, bg, Wb, sb, bb, gmap, bmap);
    // f1 = silu(Wf1 * l2norm(g*tanh(silu(Wv*img*sv+bv)) + bmax) * sf1 + bf1) -> bufB (bf16 NHWC)
    f01_kernel<<<1024, 256, 0, stream>>>(img, WvB, W1B, sv, bv, sf1, bf1, gmap, bmap, bufB);
    // f2 = silu(Wf2(3x3)*f1*sf2+bf2) -> bufA (bf16 NHWC)
    conv3x3_mfma<<<512, 256, 0, stream>>>(bufB, WB2, sf2, bf2, bufA);
    // out = l2norm((1+aw)*img + (1-aw)*(Wf3*f2 + bf3)) -> d_out (fp32 NCHW)
    final_mfma<<<1024, 256, 0, stream>>>(bufA, W3B, bf3, img, addw, out);
}